// Round 13
// baseline (1866.877 us; speedup 1.0000x reference)
//
#include <hip/hip_runtime.h>
#include <cstddef>

#define BB 32
#define TT 64
#define NN_ 2048
#define SS 2048
#define DD 256
#define GG 1024
#define FLD 264
#define SENTF 0xFF7FFFFFu   // f32 sentinel (-3.4028e38, unreachable by real data)

typedef __attribute__((ext_vector_type(8))) short short8;
typedef __attribute__((ext_vector_type(4))) float f32x4;

static __device__ inline unsigned short f2bf(float f) {
    union { float f; unsigned int u; } v; v.f = f;
    unsigned int u = v.u;
    unsigned int r = u + 0x7FFF + ((u >> 16) & 1);   // RNE
    return (unsigned short)(r >> 16);
}

static __device__ inline short8 pack8(float4 a, float4 b) {
    short8 s;
    s[0] = (short)f2bf(a.x); s[1] = (short)f2bf(a.y);
    s[2] = (short)f2bf(a.z); s[3] = (short)f2bf(a.w);
    s[4] = (short)f2bf(b.x); s[5] = (short)f2bf(b.y);
    s[6] = (short)f2bf(b.z); s[7] = (short)f2bf(b.w);
    return s;
}

// true iff neither 16-bit half of v equals 0x7F80 (bf16 +inf sentinel)
static __device__ inline bool ok32(unsigned int v) {
    unsigned int x = v ^ 0x7F807F80u;
    return (((x - 0x00010001u) & ~x & 0x80008000u) == 0u);
}

static __device__ inline unsigned long long ald64(const void* p) {
    return __hip_atomic_load((const unsigned long long*)p, __ATOMIC_RELAXED,
                             __HIP_MEMORY_SCOPE_AGENT);
}
static __device__ inline unsigned int ald32(const void* p) {
    return __hip_atomic_load((const unsigned int*)p, __ATOMIC_RELAXED,
                             __HIP_MEMORY_SCOPE_AGENT);
}
static __device__ inline void ast32(void* p, unsigned int v) {
    __hip_atomic_store((unsigned int*)p, v, __ATOMIC_RELAXED,
                       __HIP_MEMORY_SCOPE_AGENT);
}
static __device__ inline void astf(float* p, float v) {
    ast32(p, __float_as_uint(v));
}

static __device__ inline short8 pack8u(const unsigned int* q) {
    short8 s;
#pragma unroll
    for (int i = 0; i < 8; ++i) s[i] = (short)f2bf(__uint_as_float(q[i]));
    return s;
}

// backstop poll: 8 consecutive f32 until none is SENTF (passes 1st try when gated)
static __device__ inline void poll8f(const float* p, unsigned int* q) {
    for (;;) {
        unsigned long long a0 = ald64(p),     a1 = ald64(p + 2);
        unsigned long long a2 = ald64(p + 4), a3 = ald64(p + 6);
        q[0] = (unsigned int)a0; q[1] = (unsigned int)(a0 >> 32);
        q[2] = (unsigned int)a1; q[3] = (unsigned int)(a1 >> 32);
        q[4] = (unsigned int)a2; q[5] = (unsigned int)(a2 >> 32);
        q[6] = (unsigned int)a3; q[7] = (unsigned int)(a3 >> 32);
        bool ok = true;
#pragma unroll
        for (int i = 0; i < 8; ++i) ok = ok && (q[i] != SENTF);
        if (ok) return;
        __builtin_amdgcn_s_sleep(32);
    }
}

// backstop poll: 8 u32 of bf16-pairs, sentinel 0x7F80 halves
static __device__ inline void poll8h(const unsigned int* p, unsigned int* q) {
    for (;;) {
        unsigned long long a0 = ald64(p),     a1 = ald64(p + 2);
        unsigned long long a2 = ald64(p + 4), a3 = ald64(p + 6);
        q[0] = (unsigned int)a0; q[1] = (unsigned int)(a0 >> 32);
        q[2] = (unsigned int)a1; q[3] = (unsigned int)(a1 >> 32);
        q[4] = (unsigned int)a2; q[5] = (unsigned int)(a2 >> 32);
        q[6] = (unsigned int)a3; q[7] = (unsigned int)(a3 >> 32);
        bool ok = true;
#pragma unroll
        for (int i = 0; i < 8; ++i) ok = ok && ok32(q[i]);
        if (ok) return;
        __builtin_amdgcn_s_sleep(32);
    }
}

// scout gate: wave 0 polls prog[base..base+n) until min >= target, then all sync
#define GATE(progp, n, target)                                              \
    do {                                                                    \
        if (wid == 0) {                                                     \
            for (;;) {                                                      \
                int v = (lane < (n)) ? (int)ald32((progp) + lane) : 0x7FFFFFFF; \
                int mn = v;                                                 \
                for (int o = 32; o; o >>= 1) {                              \
                    int t2 = __shfl_xor(mn, o);                             \
                    mn = mn < t2 ? mn : t2;                                 \
                }                                                           \
                if (mn >= (target)) break;                                  \
                __builtin_amdgcn_s_sleep(32);                               \
            }                                                               \
        }                                                                   \
        __syncthreads();                                                    \
    } while (0)

// producer mark: drain own stores, block barrier, tid0 publishes
#define MARK(progp, val)                                                    \
    do {                                                                    \
        asm volatile("s_waitcnt vmcnt(0)" ::: "memory");                    \
        __syncthreads();                                                    \
        if (tid == 0) ast32((progp), (unsigned int)(val));                  \
    } while (0)

// ---------------- pre-kernel: poison buffers + prog zero + firstpos --------
__global__ __launch_bounds__(256) void k_pre(const int* __restrict__ gt,
                                             int* __restrict__ firstpos,
                                             unsigned int* __restrict__ r1,
                                             unsigned int* __restrict__ r2,
                                             int* __restrict__ prog) {
    size_t idx = (size_t)blockIdx.x * 256 + threadIdx.x;
    if (idx < 3686400u) r1[idx] = SENTF;          // xW | dec | attn | feat
    if (idx < 524288u)  r2[idx] = 0x7F807F80u;    // hbuf | hs16
    if (idx < 320u)     prog[idx] = 0;
    if (idx < (size_t)BB * NN_) {
        int b = (int)(idx >> 11), n = (int)(idx & 2047);
        const int* g = gt + b * TT;
        int ft = TT;
#pragma unroll
        for (int t = 0; t < TT; ++t)
            if (g[t] == n && t < ft) ft = t;
        firstpos[idx] = ft;
    }
}

// ---------------- xW tile producer (t-major rows), used by flash blocks ----
static __device__ void xw_tile(int tile,
                               const float* __restrict__ emb,
                               const int* __restrict__ gt,
                               const float* __restrict__ go,
                               const float* __restrict__ Wih,
                               const float* __restrict__ bih,
                               const float* __restrict__ bhh,
                               float* __restrict__ xW,
                               short (*SA)[72], short (*SB)[72]) {
    int m = tile >> 4, n = tile & 15;
    int tm = m * 64, tn = n * 64;
    int tid = threadIdx.x, lane = tid & 63, wid = tid >> 6;
    int wm = wid & 1, wn = wid >> 1;
    f32x4 zero = {0.f, 0.f, 0.f, 0.f};
    f32x4 acc[2][2] = {{zero, zero}, {zero, zero}};
    int row = tid >> 2, kk = (tid & 3) * 16;
    int rr = tm + row, t = rr >> 5, b = rr & 31;
    const float* arow = (t == 0) ? go
        : emb + ((size_t)b * NN_ + gt[b * TT + t - 1]) * DD;
    const float* ap = arow + kk;
    const float* bp = Wih + (size_t)(tn + row) * DD + kk;

    for (int k0 = 0; k0 < DD; k0 += 64) {
        float4 a0 = *(const float4*)(ap + k0);
        float4 a1 = *(const float4*)(ap + k0 + 4);
        float4 a2 = *(const float4*)(ap + k0 + 8);
        float4 a3 = *(const float4*)(ap + k0 + 12);
        float4 b0 = *(const float4*)(bp + k0);
        float4 b1 = *(const float4*)(bp + k0 + 4);
        float4 b2 = *(const float4*)(bp + k0 + 8);
        float4 b3 = *(const float4*)(bp + k0 + 12);
        *(short8*)&SA[row][kk]     = pack8(a0, a1);
        *(short8*)&SA[row][kk + 8] = pack8(a2, a3);
        *(short8*)&SB[row][kk]     = pack8(b0, b1);
        *(short8*)&SB[row][kk + 8] = pack8(b2, b3);
        __syncthreads();
#pragma unroll
        for (int kt = 0; kt < 2; ++kt) {
            int k8 = kt * 32 + (lane >> 4) * 8;
            short8 fa0 = *(const short8*)&SA[wm * 32 + (lane & 15)][k8];
            short8 fa1 = *(const short8*)&SA[wm * 32 + 16 + (lane & 15)][k8];
            short8 fb0 = *(const short8*)&SB[wn * 32 + (lane & 15)][k8];
            short8 fb1 = *(const short8*)&SB[wn * 32 + 16 + (lane & 15)][k8];
            acc[0][0] = __builtin_amdgcn_mfma_f32_16x16x32_bf16(fa0, fb0, acc[0][0], 0, 0, 0);
            acc[0][1] = __builtin_amdgcn_mfma_f32_16x16x32_bf16(fa0, fb1, acc[0][1], 0, 0, 0);
            acc[1][0] = __builtin_amdgcn_mfma_f32_16x16x32_bf16(fa1, fb0, acc[1][0], 0, 0, 0);
            acc[1][1] = __builtin_amdgcn_mfma_f32_16x16x32_bf16(fa1, fb1, acc[1][1], 0, 0, 0);
        }
        __syncthreads();
    }
#pragma unroll
    for (int i = 0; i < 2; ++i)
#pragma unroll
        for (int j = 0; j < 2; ++j)
#pragma unroll
            for (int r = 0; r < 4; ++r) {
                int lrow = wm * 32 + i * 16 + (lane >> 4) * 4 + r;
                int gcol = tn + wn * 32 + j * 16 + (lane & 15);
                astf(&xW[(size_t)(tm + lrow) * GG + gcol],
                     acc[i][j][r] + bih[gcol] + bhh[gcol]);
            }
}

// ---------------- mega kernel v2: progress-gated overlap -------------------
__global__ __launch_bounds__(256) void k_mega(
        const float* __restrict__ emb, const float* __restrict__ emb_mask,
        const float* __restrict__ enc, const float* __restrict__ enc_mask,
        const int* __restrict__ gt, const float* __restrict__ go,
        const float* __restrict__ Wih, const float* __restrict__ Whh,
        const float* __restrict__ bih, const float* __restrict__ bhh,
        const float* __restrict__ Wdt, const float* __restrict__ bdt,
        const float* __restrict__ Wf, const float* __restrict__ bf,
        float* __restrict__ xW, float* __restrict__ dec,
        float* __restrict__ attn, float* __restrict__ feat,
        const int* __restrict__ firstpos,
        unsigned int* __restrict__ hbuf32, unsigned int* __restrict__ hs16,
        int* __restrict__ prog, float* __restrict__ out) {
    __shared__ short SA[64][72];
    __shared__ short SB[64][72];
    __shared__ short Vt[64][264];
    __shared__ short Pt[16][72];
    __shared__ float lr16[16][4];
    __shared__ float linv[16];
    __shared__ float smsk[64];
    __shared__ float sfs16[16];

    int* prog_lstm = prog;           // [128] per (block p, wave): t+1
    int* prog_decm = prog + 128;     // [32]  per dec m-tile: 1 when done
    int* prog_flsh = prog + 160;     // [128] per flash block (b,tc): 1
    int* prog_ftm  = prog + 288;     // [32]  per feat m-tile: 1

    int bid = blockIdx.x;
    int tid = threadIdx.x, lane = tid & 63, wid = tid >> 6;
    f32x4 zero = {0.f, 0.f, 0.f, 0.f};

    if (bid < 32) {
        // ================= LSTM (proven protocol) + per-wave progress ======
        int p = bid;
        int mi = wid & 1, ni = wid >> 1;
        int jj = lane >> 4, bl = lane & 15;
        int j = p * 8 + mi * 4 + jj;
        int b = ni * 16 + bl;

        short8 afrag[8];
        {
            int rr = lane & 15;
            const float* wrow = Whh +
                (size_t)((rr & 3) * 256 + p * 8 + mi * 4 + (rr >> 2)) * DD;
#pragma unroll
            for (int kt = 0; kt < 8; ++kt) {
                short8 f;
#pragma unroll
                for (int e = 0; e < 8; ++e)
                    f[e] = (short)f2bf(wrow[kt * 32 + jj * 8 + e]);
                afrag[kt] = f;
            }
        }

        float cstate = 0.0f;
        const int wb = jj * 128 + b;
        unsigned int pw0, pw1, pw2, pw3;
        {
            const unsigned int* g0 = (const unsigned int*)(xW + (size_t)b * GG + j);
            pw0 = ald32(g0); pw1 = ald32(g0 + 256);
            pw2 = ald32(g0 + 512); pw3 = ald32(g0 + 768);
        }

        for (int t = 0; t < TT; ++t) {
            const unsigned int* g0 =
                (const unsigned int*)(xW + ((size_t)t * 32 + b) * GG + j);
            while (pw0 == SENTF || pw1 == SENTF || pw2 == SENTF || pw3 == SENTF) {
                pw0 = ald32(g0); pw1 = ald32(g0 + 256);
                pw2 = ald32(g0 + 512); pw3 = ald32(g0 + 768);
            }
            float xb0 = __uint_as_float(pw0), xb1 = __uint_as_float(pw1);
            float xb2 = __uint_as_float(pw2), xb3 = __uint_as_float(pw3);

            unsigned int nw0 = 0, nw1 = 0, nw2 = 0, nw3 = 0;
            if (t + 1 < TT) {
                const unsigned int* g1 =
                    (const unsigned int*)(xW + ((size_t)(t + 1) * 32 + b) * GG + j);
                nw0 = ald32(g1); nw1 = ald32(g1 + 256);
                nw2 = ald32(g1 + 512); nw3 = ald32(g1 + 768);
            }

            f32x4 acc = zero;
            if (t > 0) {
                const unsigned int* hb = hbuf32 + (size_t)(t - 1) * 4096;
                unsigned int q[32];
                bool ready = false;
                while (!ready) {
                    ready = true;
#pragma unroll
                    for (int kt = 0; kt < 8; ++kt)
#pragma unroll
                        for (int w4 = 0; w4 < 4; ++w4)
                            q[kt * 4 + w4] = ald32(&hb[kt * 512 + wb + w4 * 32]);
#pragma unroll
                    for (int i = 0; i < 32; ++i) ready = ready && ok32(q[i]);
                }
#pragma unroll
                for (int kt = 0; kt < 8; ++kt) {
                    union { unsigned int w[4]; short8 s; } u;
                    u.w[0] = q[kt * 4 + 0]; u.w[1] = q[kt * 4 + 1];
                    u.w[2] = q[kt * 4 + 2]; u.w[3] = q[kt * 4 + 3];
                    acc = __builtin_amdgcn_mfma_f32_16x16x32_bf16(afrag[kt], u.s, acc, 0, 0, 0);
                }
            }

            float pi = xb0 + acc[0];
            float pf = xb1 + acc[1];
            float pg = xb2 + acc[2];
            float po = xb3 + acc[3];
            float ig = 1.0f / (1.0f + __expf(-pi));
            float fg = 1.0f / (1.0f + __expf(-pf));
            float gg = tanhf(pg);
            float og = 1.0f / (1.0f + __expf(-po));
            cstate = fg * cstate + ig * gg;
            float hn = og * tanhf(cstate);

            float hnb = __shfl_down(hn, 16);
            if ((jj & 1) == 0) {
                unsigned int wv = (unsigned int)f2bf(hn) |
                                  ((unsigned int)f2bf(hnb) << 16);
                int jp = p * 4 + mi * 2 + (jj >> 1);
                ast32(&hbuf32[(size_t)t * 4096 + jp * 32 + b], wv);
                ast32(&hs16[((size_t)t * 32 + b) * 128 + jp], wv);  // t-major
            }
            asm volatile("s_waitcnt vmcnt(0)" ::: "memory");
            if (lane == 0) ast32(&prog_lstm[p * 4 + wid], t + 1);
            pw0 = nw0; pw1 = nw1; pw2 = nw2; pw3 = nw3;
        }

    } else if (bid < 48) {
        // ================= dec = hs16 @ Wdt^T + bdt (gated per m-tile) =====
        int d = bid - 32;
        int wm = wid & 1, wn = wid >> 1;
        for (int it = 0; it < 8; ++it) {
            int m = d * 2 + (it >> 2), n = it & 3;
            if ((it & 3) == 0) {
                // need hs16 rows t in {2m, 2m+1} -> all 128 lstm waves >= 2m+2
                GATE(prog_lstm, 128, 2 * m + 2);
            }
            int tm = m * 64, tn = n * 64;
            f32x4 acc[2][2] = {{zero, zero}, {zero, zero}};
            int row = tid >> 2, kk = (tid & 3) * 16;
            const unsigned int* ah = hs16 + (size_t)(tm + row) * 128;
            const float* bp = Wdt + (size_t)(tn + row) * DD + kk;
            for (int k0 = 0; k0 < DD; k0 += 64) {
                unsigned int q[8];
                poll8h(ah + ((k0 + kk) >> 1), q);
                union { unsigned int u[8]; short8 s8[2]; } uu;
#pragma unroll
                for (int i = 0; i < 8; ++i) uu.u[i] = q[i];
                *(short8*)&SA[row][kk]     = uu.s8[0];
                *(short8*)&SA[row][kk + 8] = uu.s8[1];
                float4 b0 = *(const float4*)(bp + k0);
                float4 b1 = *(const float4*)(bp + k0 + 4);
                float4 b2 = *(const float4*)(bp + k0 + 8);
                float4 b3 = *(const float4*)(bp + k0 + 12);
                *(short8*)&SB[row][kk]     = pack8(b0, b1);
                *(short8*)&SB[row][kk + 8] = pack8(b2, b3);
                __syncthreads();
#pragma unroll
                for (int kt = 0; kt < 2; ++kt) {
                    int k8 = kt * 32 + (lane >> 4) * 8;
                    short8 fa0 = *(const short8*)&SA[wm * 32 + (lane & 15)][k8];
                    short8 fa1 = *(const short8*)&SA[wm * 32 + 16 + (lane & 15)][k8];
                    short8 fb0 = *(const short8*)&SB[wn * 32 + (lane & 15)][k8];
                    short8 fb1 = *(const short8*)&SB[wn * 32 + 16 + (lane & 15)][k8];
                    acc[0][0] = __builtin_amdgcn_mfma_f32_16x16x32_bf16(fa0, fb0, acc[0][0], 0, 0, 0);
                    acc[0][1] = __builtin_amdgcn_mfma_f32_16x16x32_bf16(fa0, fb1, acc[0][1], 0, 0, 0);
                    acc[1][0] = __builtin_amdgcn_mfma_f32_16x16x32_bf16(fa1, fb0, acc[1][0], 0, 0, 0);
                    acc[1][1] = __builtin_amdgcn_mfma_f32_16x16x32_bf16(fa1, fb1, acc[1][1], 0, 0, 0);
                }
                __syncthreads();
            }
#pragma unroll
            for (int i = 0; i < 2; ++i)
#pragma unroll
                for (int jx = 0; jx < 2; ++jx)
#pragma unroll
                    for (int r = 0; r < 4; ++r) {
                        int lrow = wm * 32 + i * 16 + (lane >> 4) * 4 + r;
                        int gcol = tn + wn * 32 + jx * 16 + (lane & 15);
                        astf(&dec[(size_t)(tm + lrow) * DD + gcol],
                             acc[i][jx][r] + bdt[gcol]);
                    }
            if ((it & 3) == 3) MARK(&prog_decm[m], 1);
        }

    } else if (bid < 176) {
        // ================= flash: produce xW tiles, then gated attention ===
        int f = bid - 48;
#pragma unroll
        for (int x = 0; x < 4; ++x)
            xw_tile(f * 4 + x, emb, gt, go, Wih, bih, bhh, xW, SA, SB);
        __syncthreads();

        int b = f & 31, tc = f >> 5;
        // gate: dec m-tiles 8tc..8tc+7 done
        GATE(prog_decm + 8 * tc, 8, 1);

        short8 qf[8];
        {
            int t16 = lane & 15;
            const float* qrow = dec + ((size_t)(tc * 16 + t16) * 32 + b) * DD;
#pragma unroll
            for (int kt = 0; kt < 8; ++kt) {
                unsigned int q[8];
                poll8f(qrow + kt * 32 + (lane >> 4) * 8, q);
                qf[kt] = pack8u(q);
            }
        }
        if (tid < 64) ((float*)lr16)[tid] = 0.0f;

        f32x4 aO[4] = {zero, zero, zero, zero};
        for (int st = 0; st < 32; ++st) {
            int s0 = st * 64;
            __syncthreads();
            int row = tid >> 2, kk = (tid & 3) * 16;
#pragma unroll
            for (int kq = 0; kq < 4; ++kq) {
                const float* e = enc + ((size_t)b * SS + s0 + row) * DD + kq * 64 + kk;
                float4 e0 = *(const float4*)e;
                float4 e1 = *(const float4*)(e + 4);
                float4 e2 = *(const float4*)(e + 8);
                float4 e3 = *(const float4*)(e + 12);
                *(short8*)&Vt[row][kq * 64 + kk]     = pack8(e0, e1);
                *(short8*)&Vt[row][kq * 64 + kk + 8] = pack8(e2, e3);
            }
            if (tid < 64) smsk[tid] = enc_mask[(size_t)b * SS + s0 + tid];
            __syncthreads();

            f32x4 aS = zero;
#pragma unroll
            for (int kt = 0; kt < 8; ++kt) {
                short8 fb = *(const short8*)&Vt[wid * 16 + (lane & 15)]
                                               [kt * 32 + (lane >> 4) * 8];
                aS = __builtin_amdgcn_mfma_f32_16x16x32_bf16(qf[kt], fb, aS, 0, 0, 0);
            }
            int sl = wid * 16 + (lane & 15);
            float pen = (1.0f - smsk[sl]) * 1e20f;
#pragma unroll
            for (int r = 0; r < 4; ++r) {
                float pv = __expf(aS[r] - pen);
                int trow = (lane >> 4) * 4 + r;
                Pt[trow][sl] = (short)f2bf(pv);
                float rs = pv;
                rs += __shfl_xor(rs, 1);
                rs += __shfl_xor(rs, 2);
                rs += __shfl_xor(rs, 4);
                rs += __shfl_xor(rs, 8);
                if ((lane & 15) == 0) lr16[trow][wid] += rs;
            }
            __syncthreads();

#pragma unroll
            for (int kt = 0; kt < 2; ++kt) {
                int k8 = kt * 32 + (lane >> 4) * 8;
                short8 fa = *(const short8*)&Pt[lane & 15][k8];
#pragma unroll
                for (int jx = 0; jx < 4; ++jx) {
                    int dcc = wid * 64 + jx * 16 + (lane & 15);
                    short8 fb;
#pragma unroll
                    for (int e = 0; e < 8; ++e) fb[e] = Vt[k8 + e][dcc];
                    aO[jx] = __builtin_amdgcn_mfma_f32_16x16x32_bf16(fa, fb, aO[jx], 0, 0, 0);
                }
            }
        }
        __syncthreads();
        if (tid < 16)
            linv[tid] = 1.0f / (lr16[tid][0] + lr16[tid][1] +
                                lr16[tid][2] + lr16[tid][3]);
        __syncthreads();
#pragma unroll
        for (int jx = 0; jx < 4; ++jx)
#pragma unroll
            for (int r = 0; r < 4; ++r) {
                int trow = (lane >> 4) * 4 + r;
                int dcc = wid * 64 + jx * 16 + (lane & 15);
                astf(&attn[((size_t)(tc * 16 + trow) * 32 + b) * DD + dcc],
                     aO[jx][r] * linv[trow]);
            }
        MARK(&prog_flsh[f], 1);

    } else if (bid < 192) {
        // ================= feat = [hs16 | attn] @ Wf^T + bf (gated) ========
        int ft = bid - 176;
        int wm = wid & 1, wn = wid >> 1;
        for (int it = 0; it < 10; ++it) {
            int id = ft * 10 + it;
            int m = id / 5, n = id % 5;
            if (id % 5 == 0) {
                // attn rows t in {2m,2m+1} -> flash tc = m/8 done for all b
                GATE(prog_flsh + (m >> 3) * 32, 32, 1);
            }
            int tm = m * 64, tn = n * 64;
            f32x4 acc[2][2] = {{zero, zero}, {zero, zero}};
            int row = tid >> 2, kk = (tid & 3) * 16;
            int brow = tn + row; if (brow > 256) brow = 256;
            const unsigned int* ah = hs16 + (size_t)(tm + row) * 128;
            const float* af = attn + (size_t)(tm + row) * DD;
            const float* bp = Wf + (size_t)brow * (2 * DD) + kk;

            for (int k0 = 0; k0 < 2 * DD; k0 += 64) {
                if (k0 < DD) {
                    unsigned int q[8];
                    poll8h(ah + ((k0 + kk) >> 1), q);
                    union { unsigned int u[8]; short8 s8[2]; } uu;
#pragma unroll
                    for (int i = 0; i < 8; ++i) uu.u[i] = q[i];
                    *(short8*)&SA[row][kk]     = uu.s8[0];
                    *(short8*)&SA[row][kk + 8] = uu.s8[1];
                } else {
                    unsigned int q0[8], q1[8];
                    poll8f(af + (k0 - DD) + kk, q0);
                    poll8f(af + (k0 - DD) + kk + 8, q1);
                    *(short8*)&SA[row][kk]     = pack8u(q0);
                    *(short8*)&SA[row][kk + 8] = pack8u(q1);
                }
                float4 b0 = *(const float4*)(bp + k0);
                float4 b1 = *(const float4*)(bp + k0 + 4);
                float4 b2 = *(const float4*)(bp + k0 + 8);
                float4 b3 = *(const float4*)(bp + k0 + 12);
                *(short8*)&SB[row][kk]     = pack8(b0, b1);
                *(short8*)&SB[row][kk + 8] = pack8(b2, b3);
                __syncthreads();
#pragma unroll
                for (int kt = 0; kt < 2; ++kt) {
                    int k8 = kt * 32 + (lane >> 4) * 8;
                    short8 fa0 = *(const short8*)&SA[wm * 32 + (lane & 15)][k8];
                    short8 fa1 = *(const short8*)&SA[wm * 32 + 16 + (lane & 15)][k8];
                    short8 fb0 = *(const short8*)&SB[wn * 32 + (lane & 15)][k8];
                    short8 fb1 = *(const short8*)&SB[wn * 32 + 16 + (lane & 15)][k8];
                    acc[0][0] = __builtin_amdgcn_mfma_f32_16x16x32_bf16(fa0, fb0, acc[0][0], 0, 0, 0);
                    acc[0][1] = __builtin_amdgcn_mfma_f32_16x16x32_bf16(fa0, fb1, acc[0][1], 0, 0, 0);
                    acc[1][0] = __builtin_amdgcn_mfma_f32_16x16x32_bf16(fa1, fb0, acc[1][0], 0, 0, 0);
                    acc[1][1] = __builtin_amdgcn_mfma_f32_16x16x32_bf16(fa1, fb1, acc[1][1], 0, 0, 0);
                }
                __syncthreads();
            }
#pragma unroll
            for (int i = 0; i < 2; ++i)
#pragma unroll
                for (int jx = 0; jx < 2; ++jx)
#pragma unroll
                    for (int r = 0; r < 4; ++r) {
                        int lrow = wm * 32 + i * 16 + (lane >> 4) * 4 + r;
                        int gcol = tn + wn * 32 + jx * 16 + (lane & 15);
                        if (gcol < DD + 1)
                            astf(&feat[(size_t)(tm + lrow) * FLD + gcol],
                                 acc[i][jx][r] + bf[gcol]);
                    }
            if (id % 5 == 4) MARK(&prog_ftm[m], 1);
        }

    } else {
        // ================= score (gated per t-chunk) =======================
        int sb = bid - 192;
        int b = sb & 31, nh = sb >> 5;
        for (int tc = 0; tc < 4; ++tc) {
            // feat m-tiles 8tc..8tc+7 done
            GATE(prog_ftm + 8 * tc, 8, 1);
            short8 af[8];
            {
                int t16 = lane & 15;
                const float* frow = feat + ((size_t)(tc * 16 + t16) * 32 + b) * FLD;
#pragma unroll
                for (int kt = 0; kt < 8; ++kt) {
                    unsigned int q[8];
                    poll8f(frow + kt * 32 + (lane >> 4) * 8, q);
                    af[kt] = pack8u(q);
                }
            }
            if (tid < 16) {
                const float* fp = feat + ((size_t)(tc * 16 + tid) * 32 + b) * FLD + 256;
                unsigned int w;
                for (;;) {
                    w = ald32(fp);
                    if (w != SENTF) break;
                    __builtin_amdgcn_s_sleep(32);
                }
                sfs16[tid] = __uint_as_float(w);
            }
            __syncthreads();

            for (int nt = 0; nt < 16; ++nt) {
                int tn = nh * 1024 + nt * 64;
                f32x4 aC = zero;
                int row = tid >> 2, kk = (tid & 3) * 16;
                const float* ep = emb + ((size_t)b * NN_ + tn + row) * DD + kk;
                for (int k0 = 0; k0 < DD; k0 += 64) {
                    __syncthreads();
                    float4 e0 = *(const float4*)(ep + k0);
                    float4 e1 = *(const float4*)(ep + k0 + 4);
                    float4 e2 = *(const float4*)(ep + k0 + 8);
                    float4 e3 = *(const float4*)(ep + k0 + 12);
                    *(short8*)&SB[row][kk]     = pack8(e0, e1);
                    *(short8*)&SB[row][kk + 8] = pack8(e2, e3);
                    __syncthreads();
#pragma unroll
                    for (int kt2 = 0; kt2 < 2; ++kt2) {
                        int kt = (k0 >> 5) + kt2;
                        short8 fb = *(const short8*)&SB[wid * 16 + (lane & 15)]
                                                       [kt2 * 32 + (lane >> 4) * 8];
                        aC = __builtin_amdgcn_mfma_f32_16x16x32_bf16(af[kt], fb, aC, 0, 0, 0);
                    }
                }
#pragma unroll
                for (int r = 0; r < 4; ++r) {
                    int t16 = (lane >> 4) * 4 + r;
                    int t = tc * 16 + t16;
                    int n = tn + wid * 16 + (lane & 15);
                    float v = aC[r];
                    if (firstpos[(size_t)b * NN_ + n] < t) v += sfs16[t16];
                    v -= (1.0f - emb_mask[(size_t)b * NN_ + n]) * 1e20f;
                    out[((size_t)b * TT + t) * NN_ + n] = v;
                }
            }
            __syncthreads();   // sfs16 reuse across tc
        }
    }
}

// ---------------- launch ----------------
extern "C" void kernel_launch(void* const* d_in, const int* in_sizes, int n_in,
                              void* d_out, int out_size, void* d_ws, size_t ws_size,
                              hipStream_t stream) {
    const float* emb      = (const float*)d_in[0];
    const float* emb_mask = (const float*)d_in[1];
    const float* enc      = (const float*)d_in[2];
    const float* enc_mask = (const float*)d_in[3];
    const int*   gt       = (const int*)d_in[4];
    const float* go       = (const float*)d_in[5];
    const float* Wih      = (const float*)d_in[6];
    const float* Whh      = (const float*)d_in[7];
    const float* bih      = (const float*)d_in[8];
    const float* bhh      = (const float*)d_in[9];
    const float* Wdt      = (const float*)d_in[10];
    const float* bdt      = (const float*)d_in[11];
    const float* Wf       = (const float*)d_in[12];
    const float* bf       = (const float*)d_in[13];
    float* out = (float*)d_out;

    float* ws   = (float*)d_ws;
    float* xW   = ws;                                    // 2,097,152 f (t-major)
    float* dec  = xW + (size_t)2097152;                  //   524,288 f (t-major)
    float* attn = dec + (size_t)524288;                  //   524,288 f (t-major)
    float* feat = attn + (size_t)524288;                 //   540,672 f (t-major)
    int* firstpos = (int*)(feat + (size_t)540672);       //    65,536 i
    unsigned int* hbuf32 = (unsigned int*)(firstpos + 65536); // 262,144 u32
    unsigned int* hs16   = hbuf32 + (size_t)262144;      //   262,144 u32 (t-major)
    int* prog = (int*)(hs16 + (size_t)262144);           //       320 i

    k_pre<<<(3686400 + 255) / 256, 256, 0, stream>>>(
        gt, firstpos, (unsigned int*)xW, hbuf32, prog);

    k_mega<<<256, 256, 0, stream>>>(
        emb, emb_mask, enc, enc_mask, gt, go, Wih, Whh, bih, bhh,
        Wdt, bdt, Wf, bf, xW, dec, attn, feat, firstpos, hbuf32, hs16,
        prog, out);
}

// Round 14
// 1856.524 us; speedup vs baseline: 1.0056x; 1.0056x over previous
//
#include <hip/hip_runtime.h>
#include <cstddef>

#define BB 32
#define TT 64
#define NN_ 2048
#define SS 2048
#define DD 256
#define GG 1024
#define FLD 264
#define SENTF 0xFF7FFFFFu   // f32 sentinel (-3.4028e38, unreachable by real data)

typedef __attribute__((ext_vector_type(8))) short short8;
typedef __attribute__((ext_vector_type(4))) float f32x4;

static __device__ inline unsigned short f2bf(float f) {
    union { float f; unsigned int u; } v; v.f = f;
    unsigned int u = v.u;
    unsigned int r = u + 0x7FFF + ((u >> 16) & 1);   // RNE
    return (unsigned short)(r >> 16);
}

static __device__ inline short8 pack8(float4 a, float4 b) {
    short8 s;
    s[0] = (short)f2bf(a.x); s[1] = (short)f2bf(a.y);
    s[2] = (short)f2bf(a.z); s[3] = (short)f2bf(a.w);
    s[4] = (short)f2bf(b.x); s[5] = (short)f2bf(b.y);
    s[6] = (short)f2bf(b.z); s[7] = (short)f2bf(b.w);
    return s;
}

// true iff neither 16-bit half of v equals 0x7F80 (bf16 +inf sentinel)
static __device__ inline bool ok32(unsigned int v) {
    unsigned int x = v ^ 0x7F807F80u;
    return (((x - 0x00010001u) & ~x & 0x80008000u) == 0u);
}

static __device__ inline unsigned long long ald64(const void* p) {
    return __hip_atomic_load((const unsigned long long*)p, __ATOMIC_RELAXED,
                             __HIP_MEMORY_SCOPE_AGENT);
}
static __device__ inline unsigned int ald32(const void* p) {
    return __hip_atomic_load((const unsigned int*)p, __ATOMIC_RELAXED,
                             __HIP_MEMORY_SCOPE_AGENT);
}
static __device__ inline void ast32(void* p, unsigned int v) {
    __hip_atomic_store((unsigned int*)p, v, __ATOMIC_RELAXED,
                       __HIP_MEMORY_SCOPE_AGENT);
}
static __device__ inline void astf(float* p, float v) {
    ast32(p, __float_as_uint(v));
}

static __device__ inline short8 pack8u(const unsigned int* q) {
    short8 s;
#pragma unroll
    for (int i = 0; i < 8; ++i) s[i] = (short)f2bf(__uint_as_float(q[i]));
    return s;
}

// backstop poll: 8 consecutive f32 until none is SENTF (1st-try pass when gated)
static __device__ inline void poll8f(const float* p, unsigned int* q) {
    for (;;) {
        unsigned long long a0 = ald64(p),     a1 = ald64(p + 2);
        unsigned long long a2 = ald64(p + 4), a3 = ald64(p + 6);
        q[0] = (unsigned int)a0; q[1] = (unsigned int)(a0 >> 32);
        q[2] = (unsigned int)a1; q[3] = (unsigned int)(a1 >> 32);
        q[4] = (unsigned int)a2; q[5] = (unsigned int)(a2 >> 32);
        q[6] = (unsigned int)a3; q[7] = (unsigned int)(a3 >> 32);
        bool ok = true;
#pragma unroll
        for (int i = 0; i < 8; ++i) ok = ok && (q[i] != SENTF);
        if (ok) return;
        __builtin_amdgcn_s_sleep(32);
    }
}

// backstop poll: 8 u32 of bf16-pairs, sentinel 0x7F80 halves
static __device__ inline void poll8h(const unsigned int* p, unsigned int* q) {
    for (;;) {
        unsigned long long a0 = ald64(p),     a1 = ald64(p + 2);
        unsigned long long a2 = ald64(p + 4), a3 = ald64(p + 6);
        q[0] = (unsigned int)a0; q[1] = (unsigned int)(a0 >> 32);
        q[2] = (unsigned int)a1; q[3] = (unsigned int)(a1 >> 32);
        q[4] = (unsigned int)a2; q[5] = (unsigned int)(a2 >> 32);
        q[6] = (unsigned int)a3; q[7] = (unsigned int)(a3 >> 32);
        bool ok = true;
#pragma unroll
        for (int i = 0; i < 8; ++i) ok = ok && ok32(q[i]);
        if (ok) return;
        __builtin_amdgcn_s_sleep(32);
    }
}

// scout gate: wave 0 polls prog[0..n) (n may exceed 64) until min >= target
#define GATE(progp, n, target)                                              \
    do {                                                                    \
        if (wid == 0) {                                                     \
            for (;;) {                                                      \
                int mn = 0x7FFFFFFF;                                        \
                for (int base = 0; base < (n); base += 64) {                \
                    int ix = base + lane;                                   \
                    int v = (ix < (n)) ? (int)ald32((progp) + ix)           \
                                       : 0x7FFFFFFF;                        \
                    mn = v < mn ? v : mn;                                   \
                }                                                           \
                for (int o = 32; o; o >>= 1) {                              \
                    int t2 = __shfl_xor(mn, o);                             \
                    mn = mn < t2 ? mn : t2;                                 \
                }                                                           \
                if (mn >= (target)) break;                                  \
                __builtin_amdgcn_s_sleep(32);                               \
            }                                                               \
        }                                                                   \
        __syncthreads();                                                    \
    } while (0)

// producer mark: drain own stores, block barrier, tid0 publishes
#define MARK(progp, val)                                                    \
    do {                                                                    \
        asm volatile("s_waitcnt vmcnt(0)" ::: "memory");                    \
        __syncthreads();                                                    \
        if (tid == 0) ast32((progp), (unsigned int)(val));                  \
    } while (0)

// ---------------- K1: poison polled buffers + prog zero + firstpos ---------
__global__ __launch_bounds__(256) void k_pre(const int* __restrict__ gt,
                                             int* __restrict__ firstpos,
                                             unsigned int* __restrict__ r1,
                                             unsigned int* __restrict__ r2,
                                             int* __restrict__ prog) {
    size_t idx = (size_t)blockIdx.x * 256 + threadIdx.x;
    if (idx < 1589248u) r1[idx] = SENTF;          // dec | attn | feat
    if (idx < 524288u)  r2[idx] = 0x7F807F80u;    // hbuf | hs16
    if (idx < 320u)     prog[idx] = 0;
    if (idx < (size_t)BB * NN_) {
        int b = (int)(idx >> 11), n = (int)(idx & 2047);
        const int* g = gt + b * TT;
        int ft = TT;
#pragma unroll
        for (int t = 0; t < TT; ++t)
            if (g[t] == n && t < ft) ft = t;
        firstpos[idx] = ft;
    }
}

// ---------------- K2: xW = x @ Wih^T + bih + bhh (b-major, plain stores) ---
__global__ __launch_bounds__(256) void gemm_xw(
        const float* __restrict__ emb, const int* __restrict__ gt,
        const float* __restrict__ go, const float* __restrict__ Wih,
        float* __restrict__ xW,
        const float* __restrict__ bih, const float* __restrict__ bhh) {
    int tm = blockIdx.y * 64, tn = blockIdx.x * 64;
    __shared__ short Ab[64][72];
    __shared__ short Bb[64][72];
    int tid = threadIdx.x, lane = tid & 63, wid = tid >> 6;
    int wm = wid & 1, wn = wid >> 1;
    f32x4 zero = {0.f, 0.f, 0.f, 0.f};
    f32x4 acc[2][2] = {{zero, zero}, {zero, zero}};
    int row = tid >> 2, kk = (tid & 3) * 16;
    int m = tm + row, b = m >> 6, t = m & 63;
    const float* arow = (t == 0) ? go
        : emb + ((size_t)b * NN_ + gt[b * TT + t - 1]) * DD;
    const float* ap = arow + kk;
    const float* bp = Wih + (size_t)(tn + row) * DD + kk;

    for (int k0 = 0; k0 < DD; k0 += 64) {
        float4 a0 = *(const float4*)(ap + k0);
        float4 a1 = *(const float4*)(ap + k0 + 4);
        float4 a2 = *(const float4*)(ap + k0 + 8);
        float4 a3 = *(const float4*)(ap + k0 + 12);
        float4 b0 = *(const float4*)(bp + k0);
        float4 b1 = *(const float4*)(bp + k0 + 4);
        float4 b2 = *(const float4*)(bp + k0 + 8);
        float4 b3 = *(const float4*)(bp + k0 + 12);
        *(short8*)&Ab[row][kk]     = pack8(a0, a1);
        *(short8*)&Ab[row][kk + 8] = pack8(a2, a3);
        *(short8*)&Bb[row][kk]     = pack8(b0, b1);
        *(short8*)&Bb[row][kk + 8] = pack8(b2, b3);
        __syncthreads();
#pragma unroll
        for (int kt = 0; kt < 2; ++kt) {
            int k8 = kt * 32 + (lane >> 4) * 8;
            short8 fa0 = *(const short8*)&Ab[wm * 32 + (lane & 15)][k8];
            short8 fa1 = *(const short8*)&Ab[wm * 32 + 16 + (lane & 15)][k8];
            short8 fb0 = *(const short8*)&Bb[wn * 32 + (lane & 15)][k8];
            short8 fb1 = *(const short8*)&Bb[wn * 32 + 16 + (lane & 15)][k8];
            acc[0][0] = __builtin_amdgcn_mfma_f32_16x16x32_bf16(fa0, fb0, acc[0][0], 0, 0, 0);
            acc[0][1] = __builtin_amdgcn_mfma_f32_16x16x32_bf16(fa0, fb1, acc[0][1], 0, 0, 0);
            acc[1][0] = __builtin_amdgcn_mfma_f32_16x16x32_bf16(fa1, fb0, acc[1][0], 0, 0, 0);
            acc[1][1] = __builtin_amdgcn_mfma_f32_16x16x32_bf16(fa1, fb1, acc[1][1], 0, 0, 0);
        }
        __syncthreads();
    }
#pragma unroll
    for (int i = 0; i < 2; ++i)
#pragma unroll
        for (int j = 0; j < 2; ++j)
#pragma unroll
            for (int r = 0; r < 4; ++r) {
                int lrow = wm * 32 + i * 16 + (lane >> 4) * 4 + r;
                int gcol = tn + wn * 32 + j * 16 + (lane & 15);
                xW[(size_t)(tm + lrow) * GG + gcol] =
                    acc[i][j][r] + bih[gcol] + bhh[gcol];
            }
}

// ---------------- K3: mega v3 — LSTM (plain xW) + gated consumers ----------
__global__ __launch_bounds__(256) void k_mega(
        const float* __restrict__ emb, const float* __restrict__ emb_mask,
        const float* __restrict__ enc, const float* __restrict__ enc_mask,
        const float* __restrict__ Whh,
        const float* __restrict__ Wdt, const float* __restrict__ bdt,
        const float* __restrict__ Wf, const float* __restrict__ bf,
        const float* __restrict__ xW, float* __restrict__ dec,
        float* __restrict__ attn, float* __restrict__ feat,
        const int* __restrict__ firstpos,
        unsigned int* __restrict__ hbuf32, unsigned int* __restrict__ hs16,
        int* __restrict__ prog, float* __restrict__ out) {
    __shared__ short SA[64][72];
    __shared__ short SB[64][72];
    __shared__ short Vt[64][264];
    __shared__ short Pt[16][72];
    __shared__ float lr16[16][4];
    __shared__ float linv[16];
    __shared__ float smsk[64];
    __shared__ float sfs16[16];

    int* prog_lstm = prog;           // [128] per (block p, wave): t+1
    int* prog_decm = prog + 128;     // [32]  per dec m-tile: 1 when done
    int* prog_flsh = prog + 160;     // [128] per flash (tc*32+b): 1
    int* prog_ftm  = prog + 288;     // [32]  per feat m-tile: 1

    int bid = blockIdx.x;
    int tid = threadIdx.x, lane = tid & 63, wid = tid >> 6;
    f32x4 zero = {0.f, 0.f, 0.f, 0.f};

    if (bid < 32) {
        // ===== LSTM: round-11 proven loop (PLAIN xW loads) + prog marks ====
        int p = bid;
        int mi = wid & 1, ni = wid >> 1;
        int jj = lane >> 4, bl = lane & 15;
        int j = p * 8 + mi * 4 + jj;
        int b = ni * 16 + bl;

        short8 afrag[8];
        {
            int rr = lane & 15;
            const float* wrow = Whh +
                (size_t)((rr & 3) * 256 + p * 8 + mi * 4 + (rr >> 2)) * DD;
#pragma unroll
            for (int kt = 0; kt < 8; ++kt) {
                short8 f;
#pragma unroll
                for (int e = 0; e < 8; ++e)
                    f[e] = (short)f2bf(wrow[kt * 32 + jj * 8 + e]);
                afrag[kt] = f;
            }
        }

        float cstate = 0.0f;
        const int wb = jj * 128 + b;

        for (int t = 0; t < TT; ++t) {
            // plain xW loads (written by prior kernel — proven path)
            const float* g0 = xW + ((size_t)b * TT + t) * GG + j;
            float xb0 = g0[0], xb1 = g0[256], xb2 = g0[512], xb3 = g0[768];

            f32x4 acc = zero;
            if (t > 0) {
                const unsigned int* hb = hbuf32 + (size_t)(t - 1) * 4096;
                unsigned int q[32];
                bool ready = false;
                while (!ready) {
                    ready = true;
#pragma unroll
                    for (int kt = 0; kt < 8; ++kt)
#pragma unroll
                        for (int w4 = 0; w4 < 4; ++w4)
                            q[kt * 4 + w4] = ald32(&hb[kt * 512 + wb + w4 * 32]);
#pragma unroll
                    for (int i = 0; i < 32; ++i) ready = ready && ok32(q[i]);
                }
#pragma unroll
                for (int kt = 0; kt < 8; ++kt) {
                    union { unsigned int w[4]; short8 s; } u;
                    u.w[0] = q[kt * 4 + 0]; u.w[1] = q[kt * 4 + 1];
                    u.w[2] = q[kt * 4 + 2]; u.w[3] = q[kt * 4 + 3];
                    acc = __builtin_amdgcn_mfma_f32_16x16x32_bf16(afrag[kt], u.s, acc, 0, 0, 0);
                }
            }

            float pi = xb0 + acc[0];
            float pf = xb1 + acc[1];
            float pg = xb2 + acc[2];
            float po = xb3 + acc[3];
            float ig = 1.0f / (1.0f + __expf(-pi));
            float fg = 1.0f / (1.0f + __expf(-pf));
            float gg = tanhf(pg);
            float og = 1.0f / (1.0f + __expf(-po));
            cstate = fg * cstate + ig * gg;
            float hn = og * tanhf(cstate);

            float hnb = __shfl_down(hn, 16);
            if ((jj & 1) == 0) {
                unsigned int wv = (unsigned int)f2bf(hn) |
                                  ((unsigned int)f2bf(hnb) << 16);
                int jp = p * 4 + mi * 2 + (jj >> 1);
                ast32(&hbuf32[(size_t)t * 4096 + jp * 32 + b], wv);
                ast32(&hs16[((size_t)t * 32 + b) * 128 + jp], wv);  // t-major
            }
            asm volatile("s_waitcnt vmcnt(0)" ::: "memory");
            if (lane == 0) ast32(&prog_lstm[p * 4 + wid], t + 1);
        }

    } else if (bid < 48) {
        // ===== dec = hs16 @ Wdt^T + bdt (gated per m-tile, t-major) ========
        int d = bid - 32;
        int wm = wid & 1, wn = wid >> 1;
        for (int it = 0; it < 8; ++it) {
            int m = d * 2 + (it >> 2), n = it & 3;
            if ((it & 3) == 0) GATE(prog_lstm, 128, 2 * m + 2);
            int tm = m * 64, tn = n * 64;
            f32x4 acc[2][2] = {{zero, zero}, {zero, zero}};
            int row = tid >> 2, kk = (tid & 3) * 16;
            const unsigned int* ah = hs16 + (size_t)(tm + row) * 128;
            const float* bp = Wdt + (size_t)(tn + row) * DD + kk;
            for (int k0 = 0; k0 < DD; k0 += 64) {
                unsigned int q[8];
                poll8h(ah + ((k0 + kk) >> 1), q);
                union { unsigned int u[8]; short8 s8[2]; } uu;
#pragma unroll
                for (int i = 0; i < 8; ++i) uu.u[i] = q[i];
                *(short8*)&SA[row][kk]     = uu.s8[0];
                *(short8*)&SA[row][kk + 8] = uu.s8[1];
                float4 b0 = *(const float4*)(bp + k0);
                float4 b1 = *(const float4*)(bp + k0 + 4);
                float4 b2 = *(const float4*)(bp + k0 + 8);
                float4 b3 = *(const float4*)(bp + k0 + 12);
                *(short8*)&SB[row][kk]     = pack8(b0, b1);
                *(short8*)&SB[row][kk + 8] = pack8(b2, b3);
                __syncthreads();
#pragma unroll
                for (int kt = 0; kt < 2; ++kt) {
                    int k8 = kt * 32 + (lane >> 4) * 8;
                    short8 fa0 = *(const short8*)&SA[wm * 32 + (lane & 15)][k8];
                    short8 fa1 = *(const short8*)&SA[wm * 32 + 16 + (lane & 15)][k8];
                    short8 fb0 = *(const short8*)&SB[wn * 32 + (lane & 15)][k8];
                    short8 fb1 = *(const short8*)&SB[wn * 32 + 16 + (lane & 15)][k8];
                    acc[0][0] = __builtin_amdgcn_mfma_f32_16x16x32_bf16(fa0, fb0, acc[0][0], 0, 0, 0);
                    acc[0][1] = __builtin_amdgcn_mfma_f32_16x16x32_bf16(fa0, fb1, acc[0][1], 0, 0, 0);
                    acc[1][0] = __builtin_amdgcn_mfma_f32_16x16x32_bf16(fa1, fb0, acc[1][0], 0, 0, 0);
                    acc[1][1] = __builtin_amdgcn_mfma_f32_16x16x32_bf16(fa1, fb1, acc[1][1], 0, 0, 0);
                }
                __syncthreads();
            }
#pragma unroll
            for (int i = 0; i < 2; ++i)
#pragma unroll
                for (int jx = 0; jx < 2; ++jx)
#pragma unroll
                    for (int r = 0; r < 4; ++r) {
                        int lrow = wm * 32 + i * 16 + (lane >> 4) * 4 + r;
                        int gcol = tn + wn * 32 + jx * 16 + (lane & 15);
                        astf(&dec[(size_t)(tm + lrow) * DD + gcol],
                             acc[i][jx][r] + bdt[gcol]);
                    }
            if ((it & 3) == 3) MARK(&prog_decm[m], 1);
        }

    } else if (bid < 176) {
        // ===== flash (b,tc): gated on dec chunk, streams full enc[b] =======
        int f = bid - 48;
        int b = f & 31, tc = f >> 5;
        GATE(prog_decm + 8 * tc, 8, 1);

        short8 qf[8];
        {
            int t16 = lane & 15;
            const float* qrow = dec + ((size_t)(tc * 16 + t16) * 32 + b) * DD;
#pragma unroll
            for (int kt = 0; kt < 8; ++kt) {
                unsigned int q[8];
                poll8f(qrow + kt * 32 + (lane >> 4) * 8, q);
                qf[kt] = pack8u(q);
            }
        }
        if (tid < 64) ((float*)lr16)[tid] = 0.0f;

        f32x4 aO[4] = {zero, zero, zero, zero};
        for (int st = 0; st < 32; ++st) {
            int s0 = st * 64;
            __syncthreads();
            int row = tid >> 2, kk = (tid & 3) * 16;
#pragma unroll
            for (int kq = 0; kq < 4; ++kq) {
                const float* e = enc + ((size_t)b * SS + s0 + row) * DD + kq * 64 + kk;
                float4 e0 = *(const float4*)e;
                float4 e1 = *(const float4*)(e + 4);
                float4 e2 = *(const float4*)(e + 8);
                float4 e3 = *(const float4*)(e + 12);
                *(short8*)&Vt[row][kq * 64 + kk]     = pack8(e0, e1);
                *(short8*)&Vt[row][kq * 64 + kk + 8] = pack8(e2, e3);
            }
            if (tid < 64) smsk[tid] = enc_mask[(size_t)b * SS + s0 + tid];
            __syncthreads();

            f32x4 aS = zero;
#pragma unroll
            for (int kt = 0; kt < 8; ++kt) {
                short8 fb = *(const short8*)&Vt[wid * 16 + (lane & 15)]
                                               [kt * 32 + (lane >> 4) * 8];
                aS = __builtin_amdgcn_mfma_f32_16x16x32_bf16(qf[kt], fb, aS, 0, 0, 0);
            }
            int sl = wid * 16 + (lane & 15);
            float pen = (1.0f - smsk[sl]) * 1e20f;
#pragma unroll
            for (int r = 0; r < 4; ++r) {
                float pv = __expf(aS[r] - pen);
                int trow = (lane >> 4) * 4 + r;
                Pt[trow][sl] = (short)f2bf(pv);
                float rs = pv;
                rs += __shfl_xor(rs, 1);
                rs += __shfl_xor(rs, 2);
                rs += __shfl_xor(rs, 4);
                rs += __shfl_xor(rs, 8);
                if ((lane & 15) == 0) lr16[trow][wid] += rs;
            }
            __syncthreads();

#pragma unroll
            for (int kt = 0; kt < 2; ++kt) {
                int k8 = kt * 32 + (lane >> 4) * 8;
                short8 fa = *(const short8*)&Pt[lane & 15][k8];
#pragma unroll
                for (int jx = 0; jx < 4; ++jx) {
                    int dcc = wid * 64 + jx * 16 + (lane & 15);
                    short8 fb;
#pragma unroll
                    for (int e = 0; e < 8; ++e) fb[e] = Vt[k8 + e][dcc];
                    aO[jx] = __builtin_amdgcn_mfma_f32_16x16x32_bf16(fa, fb, aO[jx], 0, 0, 0);
                }
            }
        }
        __syncthreads();
        if (tid < 16)
            linv[tid] = 1.0f / (lr16[tid][0] + lr16[tid][1] +
                                lr16[tid][2] + lr16[tid][3]);
        __syncthreads();
#pragma unroll
        for (int jx = 0; jx < 4; ++jx)
#pragma unroll
            for (int r = 0; r < 4; ++r) {
                int trow = (lane >> 4) * 4 + r;
                int dcc = wid * 64 + jx * 16 + (lane & 15);
                astf(&attn[((size_t)(tc * 16 + trow) * 32 + b) * DD + dcc],
                     aO[jx][r] * linv[trow]);
            }
        MARK(&prog_flsh[f], 1);

    } else if (bid < 192) {
        // ===== feat = [hs16 | attn] @ Wf^T + bf (gated, t-major) ===========
        int ft = bid - 176;
        int wm = wid & 1, wn = wid >> 1;
        for (int it = 0; it < 10; ++it) {
            int id = ft * 10 + it;
            int m = id / 5, n = id % 5;
            if (id % 5 == 0) GATE(prog_flsh + (m >> 3) * 32, 32, 1);
            int tm = m * 64, tn = n * 64;
            f32x4 acc[2][2] = {{zero, zero}, {zero, zero}};
            int row = tid >> 2, kk = (tid & 3) * 16;
            int brow = tn + row; if (brow > 256) brow = 256;
            const unsigned int* ah = hs16 + (size_t)(tm + row) * 128;
            const float* af = attn + (size_t)(tm + row) * DD;
            const float* bp = Wf + (size_t)brow * (2 * DD) + kk;

            for (int k0 = 0; k0 < 2 * DD; k0 += 64) {
                if (k0 < DD) {
                    unsigned int q[8];
                    poll8h(ah + ((k0 + kk) >> 1), q);
                    union { unsigned int u[8]; short8 s8[2]; } uu;
#pragma unroll
                    for (int i = 0; i < 8; ++i) uu.u[i] = q[i];
                    *(short8*)&SA[row][kk]     = uu.s8[0];
                    *(short8*)&SA[row][kk + 8] = uu.s8[1];
                } else {
                    unsigned int q0[8], q1[8];
                    poll8f(af + (k0 - DD) + kk, q0);
                    poll8f(af + (k0 - DD) + kk + 8, q1);
                    *(short8*)&SA[row][kk]     = pack8u(q0);
                    *(short8*)&SA[row][kk + 8] = pack8u(q1);
                }
                float4 b0 = *(const float4*)(bp + k0);
                float4 b1 = *(const float4*)(bp + k0 + 4);
                float4 b2 = *(const float4*)(bp + k0 + 8);
                float4 b3 = *(const float4*)(bp + k0 + 12);
                *(short8*)&SB[row][kk]     = pack8(b0, b1);
                *(short8*)&SB[row][kk + 8] = pack8(b2, b3);
                __syncthreads();
#pragma unroll
                for (int kt = 0; kt < 2; ++kt) {
                    int k8 = kt * 32 + (lane >> 4) * 8;
                    short8 fa0 = *(const short8*)&SA[wm * 32 + (lane & 15)][k8];
                    short8 fa1 = *(const short8*)&SA[wm * 32 + 16 + (lane & 15)][k8];
                    short8 fb0 = *(const short8*)&SB[wn * 32 + (lane & 15)][k8];
                    short8 fb1 = *(const short8*)&SB[wn * 32 + 16 + (lane & 15)][k8];
                    acc[0][0] = __builtin_amdgcn_mfma_f32_16x16x32_bf16(fa0, fb0, acc[0][0], 0, 0, 0);
                    acc[0][1] = __builtin_amdgcn_mfma_f32_16x16x32_bf16(fa0, fb1, acc[0][1], 0, 0, 0);
                    acc[1][0] = __builtin_amdgcn_mfma_f32_16x16x32_bf16(fa1, fb0, acc[1][0], 0, 0, 0);
                    acc[1][1] = __builtin_amdgcn_mfma_f32_16x16x32_bf16(fa1, fb1, acc[1][1], 0, 0, 0);
                }
                __syncthreads();
            }
#pragma unroll
            for (int i = 0; i < 2; ++i)
#pragma unroll
                for (int jx = 0; jx < 2; ++jx)
#pragma unroll
                    for (int r = 0; r < 4; ++r) {
                        int lrow = wm * 32 + i * 16 + (lane >> 4) * 4 + r;
                        int gcol = tn + wn * 32 + jx * 16 + (lane & 15);
                        if (gcol < DD + 1)
                            astf(&feat[(size_t)(tm + lrow) * FLD + gcol],
                                 acc[i][jx][r] + bf[gcol]);
                    }
            if (id % 5 == 4) MARK(&prog_ftm[m], 1);
        }

    } else {
        // ===== score (gated per t-chunk) ===================================
        int sb = bid - 192;
        int b = sb & 31, nh = sb >> 5;
        for (int tc = 0; tc < 4; ++tc) {
            GATE(prog_ftm + 8 * tc, 8, 1);
            short8 af[8];
            {
                int t16 = lane & 15;
                const float* frow = feat + ((size_t)(tc * 16 + t16) * 32 + b) * FLD;
#pragma unroll
                for (int kt = 0; kt < 8; ++kt) {
                    unsigned int q[8];
                    poll8f(frow + kt * 32 + (lane >> 4) * 8, q);
                    af[kt] = pack8u(q);
                }
            }
            if (tid < 16) {
                const float* fp = feat + ((size_t)(tc * 16 + tid) * 32 + b) * FLD + 256;
                unsigned int w;
                for (;;) {
                    w = ald32(fp);
                    if (w != SENTF) break;
                    __builtin_amdgcn_s_sleep(32);
                }
                sfs16[tid] = __uint_as_float(w);
            }
            __syncthreads();

            for (int nt = 0; nt < 16; ++nt) {
                int tn = nh * 1024 + nt * 64;
                f32x4 aC = zero;
                int row = tid >> 2, kk = (tid & 3) * 16;
                const float* ep = emb + ((size_t)b * NN_ + tn + row) * DD + kk;
                for (int k0 = 0; k0 < DD; k0 += 64) {
                    __syncthreads();
                    float4 e0 = *(const float4*)(ep + k0);
                    float4 e1 = *(const float4*)(ep + k0 + 4);
                    float4 e2 = *(const float4*)(ep + k0 + 8);
                    float4 e3 = *(const float4*)(ep + k0 + 12);
                    *(short8*)&SB[row][kk]     = pack8(e0, e1);
                    *(short8*)&SB[row][kk + 8] = pack8(e2, e3);
                    __syncthreads();
#pragma unroll
                    for (int kt2 = 0; kt2 < 2; ++kt2) {
                        int kt = (k0 >> 5) + kt2;
                        short8 fb = *(const short8*)&SB[wid * 16 + (lane & 15)]
                                                       [kt2 * 32 + (lane >> 4) * 8];
                        aC = __builtin_amdgcn_mfma_f32_16x16x32_bf16(af[kt], fb, aC, 0, 0, 0);
                    }
                }
#pragma unroll
                for (int r = 0; r < 4; ++r) {
                    int t16 = (lane >> 4) * 4 + r;
                    int t = tc * 16 + t16;
                    int n = tn + wid * 16 + (lane & 15);
                    float v = aC[r];
                    if (firstpos[(size_t)b * NN_ + n] < t) v += sfs16[t16];
                    v -= (1.0f - emb_mask[(size_t)b * NN_ + n]) * 1e20f;
                    out[((size_t)b * TT + t) * NN_ + n] = v;
                }
            }
            __syncthreads();   // sfs16 reuse across tc
        }
    }
}

// ---------------- launch ----------------
extern "C" void kernel_launch(void* const* d_in, const int* in_sizes, int n_in,
                              void* d_out, int out_size, void* d_ws, size_t ws_size,
                              hipStream_t stream) {
    const float* emb      = (const float*)d_in[0];
    const float* emb_mask = (const float*)d_in[1];
    const float* enc      = (const float*)d_in[2];
    const float* enc_mask = (const float*)d_in[3];
    const int*   gt       = (const int*)d_in[4];
    const float* go       = (const float*)d_in[5];
    const float* Wih      = (const float*)d_in[6];
    const float* Whh      = (const float*)d_in[7];
    const float* bih      = (const float*)d_in[8];
    const float* bhh      = (const float*)d_in[9];
    const float* Wdt      = (const float*)d_in[10];
    const float* bdt      = (const float*)d_in[11];
    const float* Wf       = (const float*)d_in[12];
    const float* bf       = (const float*)d_in[13];
    float* out = (float*)d_out;

    float* ws   = (float*)d_ws;
    float* xW   = ws;                                    // 2,097,152 f (b-major)
    float* dec  = xW + (size_t)2097152;                  //   524,288 f (t-major)
    float* attn = dec + (size_t)524288;                  //   524,288 f (t-major)
    float* feat = attn + (size_t)524288;                 //   540,672 f (t-major)
    int* firstpos = (int*)(feat + (size_t)540672);       //    65,536 i
    unsigned int* hbuf32 = (unsigned int*)(firstpos + 65536); // 262,144 u32
    unsigned int* hs16   = hbuf32 + (size_t)262144;      //   262,144 u32 (t-major)
    int* prog = (int*)(hs16 + (size_t)262144);           //       320 i

    k_pre<<<(1589248 + 255) / 256, 256, 0, stream>>>(
        gt, firstpos, (unsigned int*)dec, hbuf32, prog);

    gemm_xw<<<dim3(GG / 64, BB * TT / 64, 1), 256, 0, stream>>>(
        emb, gt, go, Wih, xW, bih, bhh);

    k_mega<<<256, 256, 0, stream>>>(
        emb, emb_mask, enc, enc_mask, Whh, Wdt, bdt, Wf, bf,
        xW, dec, attn, feat, firstpos, hbuf32, hs16, prog, out);
}

// Round 16
// 262.536 us; speedup vs baseline: 7.1109x; 7.0715x over previous
//
#include <hip/hip_runtime.h>
#include <cstddef>

#define BB 32
#define TT 64
#define NN_ 2048
#define SS 2048
#define DD 256
#define GG 1024
#define LP 32   // LSTM blocks (col-slices)
#define FLD 264 // padded feat leading dim (16B-aligned rows, >=258)

typedef __attribute__((ext_vector_type(8))) short short8;
typedef __attribute__((ext_vector_type(4))) float f32x4;

static __device__ inline unsigned short f2bf(float f) {
    union { float f; unsigned int u; } v; v.f = f;
    unsigned int u = v.u;
    unsigned int r = u + 0x7FFF + ((u >> 16) & 1);   // RNE
    return (unsigned short)(r >> 16);
}

static __device__ inline short8 pack8(float4 a, float4 b) {
    short8 s;
    s[0] = (short)f2bf(a.x); s[1] = (short)f2bf(a.y);
    s[2] = (short)f2bf(a.z); s[3] = (short)f2bf(a.w);
    s[4] = (short)f2bf(b.x); s[5] = (short)f2bf(b.y);
    s[6] = (short)f2bf(b.z); s[7] = (short)f2bf(b.w);
    return s;
}

// true iff neither 16-bit half of v equals 0x7F80 (bf16 +inf sentinel)
static __device__ inline bool ok32(unsigned int v) {
    unsigned int x = v ^ 0x7F807F80u;
    return (((x - 0x00010001u) & ~x & 0x80008000u) == 0u);
}

static __device__ inline unsigned long long ald64(const void* p) {
    return __hip_atomic_load((const unsigned long long*)p, __ATOMIC_RELAXED,
                             __HIP_MEMORY_SCOPE_AGENT);
}

// sentinel-validated poll of 8 u32 bf16-pairs (32B aligned), sleep backoff
static __device__ inline void poll8h(const unsigned int* p, unsigned int* q) {
    for (;;) {
        unsigned long long a0 = ald64(p),     a1 = ald64(p + 2);
        unsigned long long a2 = ald64(p + 4), a3 = ald64(p + 6);
        q[0] = (unsigned int)a0; q[1] = (unsigned int)(a0 >> 32);
        q[2] = (unsigned int)a1; q[3] = (unsigned int)(a1 >> 32);
        q[4] = (unsigned int)a2; q[5] = (unsigned int)(a2 >> 32);
        q[6] = (unsigned int)a3; q[7] = (unsigned int)(a3 >> 32);
        bool ok = true;
#pragma unroll
        for (int i = 0; i < 8; ++i) ok = ok && ok32(q[i]);
        if (ok) return;
        __builtin_amdgcn_s_sleep(16);
    }
}

// ---------------- prep: firstpos scan + hbuf/hs16 poison -------------------
__global__ __launch_bounds__(256) void k_prep(const int* __restrict__ gt,
                                              int* __restrict__ firstpos,
                                              unsigned int* __restrict__ hbuf32) {
    int T = blockIdx.x * 256 + threadIdx.x;   // 0..65535 over B*N
    int b = T >> 11, n = T & 2047;
    const int* g = gt + b * TT;
    int ft = TT;
#pragma unroll
    for (int t = 0; t < TT; ++t)
        if (g[t] == n && t < ft) ft = t;
    firstpos[T] = ft;
#pragma unroll
    for (int k = 0; k < 8; ++k)               // hbuf (4x64K) + hs16 (4x64K)
        hbuf32[T + 65536 * k] = 0x7F807F80u;  // bf16 +inf pairs
}

// ---------------- xW GEMM with fused teacher-forcing gather ----------------
__global__ __launch_bounds__(256) void gemm_xw(
        const float* __restrict__ emb, const int* __restrict__ gt,
        const float* __restrict__ go, const float* __restrict__ Wih,
        float* __restrict__ xW,
        const float* __restrict__ bih, const float* __restrict__ bhh) {
    int tm = blockIdx.y * 64, tn = blockIdx.x * 64;
    __shared__ short Ab[64][72];
    __shared__ short Bb[64][72];
    int tid = threadIdx.x, lane = tid & 63, wid = tid >> 6;
    int wm = wid & 1, wn = wid >> 1;
    f32x4 zero = {0.f, 0.f, 0.f, 0.f};
    f32x4 acc[2][2] = {{zero, zero}, {zero, zero}};
    int row = tid >> 2, kk = (tid & 3) * 16;
    int m = tm + row, b = m >> 6, t = m & 63;
    const float* arow = (t == 0) ? go
        : emb + ((size_t)b * NN_ + gt[b * TT + t - 1]) * DD;
    const float* ap = arow + kk;
    const float* bp = Wih + (size_t)(tn + row) * DD + kk;

    for (int k0 = 0; k0 < DD; k0 += 64) {
        float4 a0 = *(const float4*)(ap + k0);
        float4 a1 = *(const float4*)(ap + k0 + 4);
        float4 a2 = *(const float4*)(ap + k0 + 8);
        float4 a3 = *(const float4*)(ap + k0 + 12);
        float4 b0 = *(const float4*)(bp + k0);
        float4 b1 = *(const float4*)(bp + k0 + 4);
        float4 b2 = *(const float4*)(bp + k0 + 8);
        float4 b3 = *(const float4*)(bp + k0 + 12);
        *(short8*)&Ab[row][kk]     = pack8(a0, a1);
        *(short8*)&Ab[row][kk + 8] = pack8(a2, a3);
        *(short8*)&Bb[row][kk]     = pack8(b0, b1);
        *(short8*)&Bb[row][kk + 8] = pack8(b2, b3);
        __syncthreads();
#pragma unroll
        for (int kt = 0; kt < 2; ++kt) {
            int k8 = kt * 32 + (lane >> 4) * 8;
            short8 fa0 = *(const short8*)&Ab[wm * 32 + (lane & 15)][k8];
            short8 fa1 = *(const short8*)&Ab[wm * 32 + 16 + (lane & 15)][k8];
            short8 fb0 = *(const short8*)&Bb[wn * 32 + (lane & 15)][k8];
            short8 fb1 = *(const short8*)&Bb[wn * 32 + 16 + (lane & 15)][k8];
            acc[0][0] = __builtin_amdgcn_mfma_f32_16x16x32_bf16(fa0, fb0, acc[0][0], 0, 0, 0);
            acc[0][1] = __builtin_amdgcn_mfma_f32_16x16x32_bf16(fa0, fb1, acc[0][1], 0, 0, 0);
            acc[1][0] = __builtin_amdgcn_mfma_f32_16x16x32_bf16(fa1, fb0, acc[1][0], 0, 0, 0);
            acc[1][1] = __builtin_amdgcn_mfma_f32_16x16x32_bf16(fa1, fb1, acc[1][1], 0, 0, 0);
        }
        __syncthreads();
    }

#pragma unroll
    for (int i = 0; i < 2; ++i)
#pragma unroll
        for (int j = 0; j < 2; ++j)
#pragma unroll
            for (int r = 0; r < 4; ++r) {
                int lrow = wm * 32 + i * 16 + (lane >> 4) * 4 + r;
                int gcol = tn + wn * 32 + j * 16 + (lane & 15);
                xW[(size_t)(tm + lrow) * GG + gcol] =
                    acc[i][j][r] + bih[gcol] + bhh[gcol];
            }
}

// ---------------- generic bf16 MFMA NT GEMM (f32 A/B) ----------------------
__global__ __launch_bounds__(256) void gemm_bf16_nt(
        const float* __restrict__ A, const float* __restrict__ Bm,
        float* __restrict__ C, int K, int lda, int ldb, int ldc,
        long sA, long sB, long sC, int Nlim,
        const float* __restrict__ bias1,
        const int* __restrict__ firstpos, const float* __restrict__ emb_mask,
        int fscol) {
    int bz = blockIdx.z;
    A += (size_t)bz * sA; Bm += (size_t)bz * sB; C += (size_t)bz * sC;
    int tm = blockIdx.y * 64, tn = blockIdx.x * 64;
    __shared__ short Ab[64][72];
    __shared__ short Bb[64][72];
    __shared__ float sfs[64];
    int tid = threadIdx.x, lane = tid & 63, wid = tid >> 6;
    int wm = wid & 1, wn = wid >> 1;

    if (fscol >= 0 && tid < 64) sfs[tid] = A[(size_t)(tm + tid) * lda + fscol];

    f32x4 zero = {0.f, 0.f, 0.f, 0.f};
    f32x4 acc[2][2] = {{zero, zero}, {zero, zero}};

    int row = tid >> 2, kk = (tid & 3) * 16;
    int brow = tn + row; if (brow >= Nlim) brow = Nlim - 1;
    const float* ap = &A[(size_t)(tm + row) * lda + kk];
    const float* bp = &Bm[(size_t)brow * ldb + kk];

    for (int k0 = 0; k0 < K; k0 += 64) {
        float4 a0 = *(const float4*)(ap + k0);
        float4 a1 = *(const float4*)(ap + k0 + 4);
        float4 a2 = *(const float4*)(ap + k0 + 8);
        float4 a3 = *(const float4*)(ap + k0 + 12);
        float4 b0 = *(const float4*)(bp + k0);
        float4 b1 = *(const float4*)(bp + k0 + 4);
        float4 b2 = *(const float4*)(bp + k0 + 8);
        float4 b3 = *(const float4*)(bp + k0 + 12);
        *(short8*)&Ab[row][kk]     = pack8(a0, a1);
        *(short8*)&Ab[row][kk + 8] = pack8(a2, a3);
        *(short8*)&Bb[row][kk]     = pack8(b0, b1);
        *(short8*)&Bb[row][kk + 8] = pack8(b2, b3);
        __syncthreads();
#pragma unroll
        for (int kt = 0; kt < 2; ++kt) {
            int k8 = kt * 32 + (lane >> 4) * 8;
            short8 fa0 = *(const short8*)&Ab[wm * 32 + (lane & 15)][k8];
            short8 fa1 = *(const short8*)&Ab[wm * 32 + 16 + (lane & 15)][k8];
            short8 fb0 = *(const short8*)&Bb[wn * 32 + (lane & 15)][k8];
            short8 fb1 = *(const short8*)&Bb[wn * 32 + 16 + (lane & 15)][k8];
            acc[0][0] = __builtin_amdgcn_mfma_f32_16x16x32_bf16(fa0, fb0, acc[0][0], 0, 0, 0);
            acc[0][1] = __builtin_amdgcn_mfma_f32_16x16x32_bf16(fa0, fb1, acc[0][1], 0, 0, 0);
            acc[1][0] = __builtin_amdgcn_mfma_f32_16x16x32_bf16(fa1, fb0, acc[1][0], 0, 0, 0);
            acc[1][1] = __builtin_amdgcn_mfma_f32_16x16x32_bf16(fa1, fb1, acc[1][1], 0, 0, 0);
        }
        __syncthreads();
    }

#pragma unroll
    for (int i = 0; i < 2; ++i) {
#pragma unroll
        for (int j = 0; j < 2; ++j) {
#pragma unroll
            for (int r = 0; r < 4; ++r) {
                int lrow = wm * 32 + i * 16 + (lane >> 4) * 4 + r;
                int gcol = tn + wn * 32 + j * 16 + (lane & 15);
                if (gcol < Nlim) {
                    float v = acc[i][j][r];
                    if (bias1) v += bias1[gcol];
                    if (firstpos) {
                        int grow = tm + lrow;
                        if (firstpos[(size_t)bz * NN_ + gcol] < grow) v += sfs[lrow];
                        v -= (1.0f - emb_mask[(size_t)bz * NN_ + gcol]) * 1e20f;
                    }
                    C[(size_t)(tm + lrow) * ldc + gcol] = v;
                }
            }
        }
    }
}

// ---------------- feat = [hs16 | attn] @ Wf^T + bf (fused cat) -------------
__global__ __launch_bounds__(256) void gemm_feat(
        const unsigned int* __restrict__ hs16, const float* __restrict__ attn,
        const float* __restrict__ Wf, const float* __restrict__ bf,
        float* __restrict__ feat) {
    int tm = blockIdx.y * 64, tn = blockIdx.x * 64;
    __shared__ short Ab[64][72];
    __shared__ short Bb[64][72];
    int tid = threadIdx.x, lane = tid & 63, wid = tid >> 6;
    int wm = wid & 1, wn = wid >> 1;
    f32x4 zero = {0.f, 0.f, 0.f, 0.f};
    f32x4 acc[2][2] = {{zero, zero}, {zero, zero}};
    int row = tid >> 2, kk = (tid & 3) * 16;
    int brow = tn + row; if (brow > 256) brow = 256;
    const short* a16 = (const short*)hs16 + (size_t)(tm + row) * DD + kk;
    const float* af  = attn + (size_t)(tm + row) * DD + kk;
    const float* bp  = Wf + (size_t)brow * (2 * DD) + kk;

    for (int k0 = 0; k0 < 2 * DD; k0 += 64) {
        if (k0 < DD) {
            *(short8*)&Ab[row][kk]     = *(const short8*)(a16 + k0);
            *(short8*)&Ab[row][kk + 8] = *(const short8*)(a16 + k0 + 8);
        } else {
            float4 a0 = *(const float4*)(af + k0 - DD);
            float4 a1 = *(const float4*)(af + k0 - DD + 4);
            float4 a2 = *(const float4*)(af + k0 - DD + 8);
            float4 a3 = *(const float4*)(af + k0 - DD + 12);
            *(short8*)&Ab[row][kk]     = pack8(a0, a1);
            *(short8*)&Ab[row][kk + 8] = pack8(a2, a3);
        }
        float4 b0 = *(const float4*)(bp + k0);
        float4 b1 = *(const float4*)(bp + k0 + 4);
        float4 b2 = *(const float4*)(bp + k0 + 8);
        float4 b3 = *(const float4*)(bp + k0 + 12);
        *(short8*)&Bb[row][kk]     = pack8(b0, b1);
        *(short8*)&Bb[row][kk + 8] = pack8(b2, b3);
        __syncthreads();
#pragma unroll
        for (int kt = 0; kt < 2; ++kt) {
            int k8 = kt * 32 + (lane >> 4) * 8;
            short8 fa0 = *(const short8*)&Ab[wm * 32 + (lane & 15)][k8];
            short8 fa1 = *(const short8*)&Ab[wm * 32 + 16 + (lane & 15)][k8];
            short8 fb0 = *(const short8*)&Bb[wn * 32 + (lane & 15)][k8];
            short8 fb1 = *(const short8*)&Bb[wn * 32 + 16 + (lane & 15)][k8];
            acc[0][0] = __builtin_amdgcn_mfma_f32_16x16x32_bf16(fa0, fb0, acc[0][0], 0, 0, 0);
            acc[0][1] = __builtin_amdgcn_mfma_f32_16x16x32_bf16(fa0, fb1, acc[0][1], 0, 0, 0);
            acc[1][0] = __builtin_amdgcn_mfma_f32_16x16x32_bf16(fa1, fb0, acc[1][0], 0, 0, 0);
            acc[1][1] = __builtin_amdgcn_mfma_f32_16x16x32_bf16(fa1, fb1, acc[1][1], 0, 0, 0);
        }
        __syncthreads();
    }

#pragma unroll
    for (int i = 0; i < 2; ++i)
#pragma unroll
        for (int j = 0; j < 2; ++j)
#pragma unroll
            for (int r = 0; r < 4; ++r) {
                int lrow = wm * 32 + i * 16 + (lane >> 4) * 4 + r;
                int gcol = tn + wn * 32 + j * 16 + (lane & 15);
                if (gcol < DD + 1)
                    feat[(size_t)(tm + lrow) * FLD + gcol] = acc[i][j][r] + bf[gcol];
            }
}

// ---------------- flash attention: raw+softmax+attn fused ------------------
__global__ __launch_bounds__(256) void k_flash(const float* __restrict__ dec,
                                               const float* __restrict__ enc,
                                               const float* __restrict__ enc_mask,
                                               float* __restrict__ part,
                                               float* __restrict__ lsum) {
    int c = blockIdx.x;            // s-chunk 0..7
    int b = blockIdx.z;
    const float* Qf = dec + (size_t)b * TT * DD;
    const float* Eb = enc + (size_t)b * SS * DD;

    __shared__ short Vt[64][264];  // enc tile bf16 [s][d]
    __shared__ short Pt[64][72];   // P bf16 [t][s]
    __shared__ float l_run[64][2];
    __shared__ float smsk[64];

    int tid = threadIdx.x, lane = tid & 63, wid = tid >> 6;
    int wm = wid & 1, wn = wid >> 1;
    int row = tid >> 2, kk = (tid & 3) * 16;

    short8 qf[8][2];
#pragma unroll
    for (int kt = 0; kt < 8; ++kt) {
        int kb = kt * 32 + (lane >> 4) * 8;
        const float* q0 = Qf + (size_t)(wm * 32 + (lane & 15)) * DD + kb;
        const float* q1 = Qf + (size_t)(wm * 32 + 16 + (lane & 15)) * DD + kb;
        qf[kt][0] = pack8(*(const float4*)q0, *(const float4*)(q0 + 4));
        qf[kt][1] = pack8(*(const float4*)q1, *(const float4*)(q1 + 4));
    }

    if (tid < 128) ((float*)l_run)[tid] = 0.0f;

    f32x4 zero = {0.f, 0.f, 0.f, 0.f};
    f32x4 aO[4][2][2];
#pragma unroll
    for (int dp = 0; dp < 4; ++dp)
#pragma unroll
        for (int i = 0; i < 2; ++i)
#pragma unroll
            for (int j = 0; j < 2; ++j) aO[dp][i][j] = zero;

    for (int kt64 = 0; kt64 < 4; ++kt64) {
        int s0 = c * 256 + kt64 * 64;
        __syncthreads();
#pragma unroll
        for (int kq = 0; kq < 4; ++kq) {
            const float* e = Eb + (size_t)(s0 + row) * DD + kq * 64 + kk;
            float4 e0 = *(const float4*)e;
            float4 e1 = *(const float4*)(e + 4);
            float4 e2 = *(const float4*)(e + 8);
            float4 e3 = *(const float4*)(e + 12);
            *(short8*)&Vt[row][kq * 64 + kk]     = pack8(e0, e1);
            *(short8*)&Vt[row][kq * 64 + kk + 8] = pack8(e2, e3);
        }
        if (tid < 64) smsk[tid] = enc_mask[(size_t)b * SS + s0 + tid];
        __syncthreads();

        f32x4 aS[2][2] = {{zero, zero}, {zero, zero}};
#pragma unroll
        for (int kt = 0; kt < 8; ++kt) {
            int k8 = kt * 32 + (lane >> 4) * 8;
            short8 fb0 = *(const short8*)&Vt[wn * 32 + (lane & 15)][k8];
            short8 fb1 = *(const short8*)&Vt[wn * 32 + 16 + (lane & 15)][k8];
            aS[0][0] = __builtin_amdgcn_mfma_f32_16x16x32_bf16(qf[kt][0], fb0, aS[0][0], 0, 0, 0);
            aS[0][1] = __builtin_amdgcn_mfma_f32_16x16x32_bf16(qf[kt][0], fb1, aS[0][1], 0, 0, 0);
            aS[1][0] = __builtin_amdgcn_mfma_f32_16x16x32_bf16(qf[kt][1], fb0, aS[1][0], 0, 0, 0);
            aS[1][1] = __builtin_amdgcn_mfma_f32_16x16x32_bf16(qf[kt][1], fb1, aS[1][1], 0, 0, 0);
        }

        int scol0 = wn * 32 + (lane & 15);
        float pen0 = (1.0f - smsk[scol0]) * 1e20f;
        float pen1 = (1.0f - smsk[scol0 + 16]) * 1e20f;
#pragma unroll
        for (int i = 0; i < 2; ++i)
#pragma unroll
            for (int r = 0; r < 4; ++r) {
                float p0 = __expf(aS[i][0][r] - pen0);
                float p1 = __expf(aS[i][1][r] - pen1);
                int trow = wm * 32 + i * 16 + (lane >> 4) * 4 + r;
                Pt[trow][scol0] = (short)f2bf(p0);
                Pt[trow][scol0 + 16] = (short)f2bf(p1);
                float rs = p0 + p1;
                rs += __shfl_xor(rs, 1);
                rs += __shfl_xor(rs, 2);
                rs += __shfl_xor(rs, 4);
                rs += __shfl_xor(rs, 8);
                if ((lane & 15) == 0) l_run[trow][wn] += rs;
            }
        __syncthreads();

#pragma unroll
        for (int kt = 0; kt < 2; ++kt) {
            int k8 = kt * 32 + (lane >> 4) * 8;
            short8 fa0 = *(const short8*)&Pt[wm * 32 + (lane & 15)][k8];
            short8 fa1 = *(const short8*)&Pt[wm * 32 + 16 + (lane & 15)][k8];
#pragma unroll
            for (int dp = 0; dp < 4; ++dp) {
                int dc = dp * 64 + wn * 32 + (lane & 15);
                short8 fb0, fb1;
#pragma unroll
                for (int e = 0; e < 8; ++e) {
                    fb0[e] = Vt[k8 + e][dc];
                    fb1[e] = Vt[k8 + e][dc + 16];
                }
                aO[dp][0][0] = __builtin_amdgcn_mfma_f32_16x16x32_bf16(fa0, fb0, aO[dp][0][0], 0, 0, 0);
                aO[dp][0][1] = __builtin_amdgcn_mfma_f32_16x16x32_bf16(fa0, fb1, aO[dp][0][1], 0, 0, 0);
                aO[dp][1][0] = __builtin_amdgcn_mfma_f32_16x16x32_bf16(fa1, fb0, aO[dp][1][0], 0, 0, 0);
                aO[dp][1][1] = __builtin_amdgcn_mfma_f32_16x16x32_bf16(fa1, fb1, aO[dp][1][1], 0, 0, 0);
            }
        }
    }
    __syncthreads();

    float* pp = part + ((size_t)(b * 8 + c) * 64) * 256;
#pragma unroll
    for (int dp = 0; dp < 4; ++dp)
#pragma unroll
        for (int i = 0; i < 2; ++i)
#pragma unroll
            for (int j = 0; j < 2; ++j)
#pragma unroll
                for (int r = 0; r < 4; ++r) {
                    int trow = wm * 32 + i * 16 + (lane >> 4) * 4 + r;
                    int dcol = dp * 64 + wn * 32 + j * 16 + (lane & 15);
                    pp[(size_t)trow * 256 + dcol] = aO[dp][i][j][r];
                }
    if (tid < 64)
        lsum[(size_t)(b * 8 + c) * 64 + tid] = l_run[tid][0] + l_run[tid][1];
}

// ---------------- merge flash partials: attn = sum acc_c / sum l_c ---------
__global__ __launch_bounds__(256) void k_amerge(const float* __restrict__ part,
                                                const float* __restrict__ lsum,
                                                float* __restrict__ attn) {
    int bt = blockIdx.x;           // 0..2047
    int b = bt >> 6, t = bt & 63, d = threadIdx.x;
    float a = 0.0f, L = 0.0f;
#pragma unroll
    for (int c = 0; c < 8; ++c) {
        a += part[((size_t)(b * 8 + c) * 64 + t) * 256 + d];
        L += lsum[(size_t)(b * 8 + c) * 64 + t];
    }
    attn[(size_t)bt * 256 + d] = a / L;
}

// ---------------- LSTM (proven round-6/11) + fused dec tail ----------------
// 32 blocks x 256 threads; flagless data-poll protocol (sentinel 0x7F80);
// publishes hbuf32[t][j>>1][b] AND row-major bf16 hs16[bt][j>>1] — BOTH via
// relaxed agent atomic stores (plain stores are NOT intra-kernel visible
// across XCDs: round-15 lesson). After the recurrence, block p computes dec
// rows for BATCH p reading hs16 via sentinel-validated poll8h.
__global__ __launch_bounds__(256) void k_lstm_mfma(const float* __restrict__ xW,
                                                   const float* __restrict__ Whh,
                                                   unsigned int* __restrict__ hbuf32,
                                                   unsigned int* __restrict__ hs16,
                                                   const float* __restrict__ Wdt,
                                                   const float* __restrict__ bdt,
                                                   float* __restrict__ dec) {
    __shared__ short SA[64][72];
    __shared__ short SB[64][72];
    int p = blockIdx.x;            // 0..31 col-slice
    int tid = threadIdx.x;
    int lane = tid & 63;
    int wid = tid >> 6;            // 4 waves
    int mi = wid & 1;              // unit-halves (4 units each)
    int ni = wid >> 1;             // batch-halves (16 batches each)
    int jj = lane >> 4;            // 0..3 unit within mi-group
    int bl = lane & 15;            // batch within ni-group
    int j = p * 8 + mi * 4 + jj;   // hidden unit this lane activates
    int b = ni * 16 + bl;          // batch this lane activates

    short8 afrag[8];
    {
        int rr = lane & 15;
        const float* wrow = Whh + (size_t)((rr & 3) * 256 + p * 8 + mi * 4 + (rr >> 2)) * DD;
#pragma unroll
        for (int kt = 0; kt < 8; ++kt) {
            short8 f;
#pragma unroll
            for (int e = 0; e < 8; ++e)
                f[e] = (short)f2bf(wrow[kt * 32 + (lane >> 4) * 8 + e]);
            afrag[kt] = f;
        }
    }

    float cstate = 0.0f;
    const int wb = jj * 128 + b;   // word base: (jj*4 + w4)*32 + b
    f32x4 zero = {0.f, 0.f, 0.f, 0.f};

    for (int t = 0; t < TT; ++t) {
        const float* g0 = xW + ((size_t)b * TT + t) * GG + j;
        float xb0 = g0[0], xb1 = g0[256], xb2 = g0[512], xb3 = g0[768];

        f32x4 acc = zero;
        if (t > 0) {
            const unsigned int* hb = hbuf32 + (size_t)(t - 1) * 4096;
            unsigned int q[32];
            bool ready = false;
            while (!ready) {
                ready = true;
#pragma unroll
                for (int kt = 0; kt < 8; ++kt)
#pragma unroll
                    for (int w4 = 0; w4 < 4; ++w4)
                        q[kt * 4 + w4] = __hip_atomic_load(&hb[kt * 512 + wb + w4 * 32],
                            __ATOMIC_RELAXED, __HIP_MEMORY_SCOPE_AGENT);
#pragma unroll
                for (int i = 0; i < 32; ++i) ready = ready && ok32(q[i]);
            }
#pragma unroll
            for (int kt = 0; kt < 8; ++kt) {
                union { unsigned int w[4]; short8 s; } u;
                u.w[0] = q[kt * 4 + 0]; u.w[1] = q[kt * 4 + 1];
                u.w[2] = q[kt * 4 + 2]; u.w[3] = q[kt * 4 + 3];
                acc = __builtin_amdgcn_mfma_f32_16x16x32_bf16(afrag[kt], u.s, acc, 0, 0, 0);
            }
        }

        float pi = xb0 + acc[0];
        float pf = xb1 + acc[1];
        float pg = xb2 + acc[2];
        float po = xb3 + acc[3];
        float ig = 1.0f / (1.0f + __expf(-pi));
        float fg = 1.0f / (1.0f + __expf(-pf));
        float gg = tanhf(pg);
        float og = 1.0f / (1.0f + __expf(-po));
        cstate = fg * cstate + ig * gg;
        float hn = og * tanhf(cstate);

        float hnb = __shfl_down(hn, 16);
        if ((jj & 1) == 0) {
            unsigned int wv = (unsigned int)f2bf(hn) |
                              ((unsigned int)f2bf(hnb) << 16);
            int jp = p * 4 + mi * 2 + (jj >> 1);
            __hip_atomic_store(&hbuf32[(size_t)t * 4096 + jp * 32 + b],
                               wv, __ATOMIC_RELAXED, __HIP_MEMORY_SCOPE_AGENT);
            __hip_atomic_store(&hs16[((size_t)b * TT + t) * 128 + jp],
                               wv, __ATOMIC_RELAXED, __HIP_MEMORY_SCOPE_AGENT);
        }
        asm volatile("s_waitcnt vmcnt(0)" ::: "memory");
    }

    // ---- fused dec: batch p's 64 rows (b-major tile p), 4 n-tiles ----
    {
        int wm = wid & 1, wn = wid >> 1;
        int row = tid >> 2, kk = (tid & 3) * 16;
        int tm = p * 64;
        const unsigned int* ah = hs16 + (size_t)(tm + row) * 128;
        for (int n = 0; n < 4; ++n) {
            int tn = n * 64;
            f32x4 acc2[2][2] = {{zero, zero}, {zero, zero}};
            const float* bp = Wdt + (size_t)(tn + row) * DD + kk;
            for (int k0 = 0; k0 < DD; k0 += 64) {
                unsigned int q[8];
                poll8h(ah + ((k0 + kk) >> 1), q);
                union { unsigned int u[8]; short8 s8[2]; } uu;
#pragma unroll
                for (int i = 0; i < 8; ++i) uu.u[i] = q[i];
                *(short8*)&SA[row][kk]     = uu.s8[0];
                *(short8*)&SA[row][kk + 8] = uu.s8[1];
                float4 b0 = *(const float4*)(bp + k0);
                float4 b1 = *(const float4*)(bp + k0 + 4);
                float4 b2 = *(const float4*)(bp + k0 + 8);
                float4 b3 = *(const float4*)(bp + k0 + 12);
                *(short8*)&SB[row][kk]     = pack8(b0, b1);
                *(short8*)&SB[row][kk + 8] = pack8(b2, b3);
                __syncthreads();
#pragma unroll
                for (int kt = 0; kt < 2; ++kt) {
                    int k8 = kt * 32 + (lane >> 4) * 8;
                    short8 fa0 = *(const short8*)&SA[wm * 32 + (lane & 15)][k8];
                    short8 fa1 = *(const short8*)&SA[wm * 32 + 16 + (lane & 15)][k8];
                    short8 fb0 = *(const short8*)&SB[wn * 32 + (lane & 15)][k8];
                    short8 fb1 = *(const short8*)&SB[wn * 32 + 16 + (lane & 15)][k8];
                    acc2[0][0] = __builtin_amdgcn_mfma_f32_16x16x32_bf16(fa0, fb0, acc2[0][0], 0, 0, 0);
                    acc2[0][1] = __builtin_amdgcn_mfma_f32_16x16x32_bf16(fa0, fb1, acc2[0][1], 0, 0, 0);
                    acc2[1][0] = __builtin_amdgcn_mfma_f32_16x16x32_bf16(fa1, fb0, acc2[1][0], 0, 0, 0);
                    acc2[1][1] = __builtin_amdgcn_mfma_f32_16x16x32_bf16(fa1, fb1, acc2[1][1], 0, 0, 0);
                }
                __syncthreads();
            }
#pragma unroll
            for (int i = 0; i < 2; ++i)
#pragma unroll
                for (int jx = 0; jx < 2; ++jx)
#pragma unroll
                    for (int r = 0; r < 4; ++r) {
                        int lrow = wm * 32 + i * 16 + (lane >> 4) * 4 + r;
                        int gcol = tn + wn * 32 + jx * 16 + (lane & 15);
                        dec[(size_t)(tm + lrow) * DD + gcol] = acc2[i][jx][r] + bdt[gcol];
                    }
        }
    }
}

// ---------------- launch ----------------
extern "C" void kernel_launch(void* const* d_in, const int* in_sizes, int n_in,
                              void* d_out, int out_size, void* d_ws, size_t ws_size,
                              hipStream_t stream) {
    const float* emb      = (const float*)d_in[0];
    const float* emb_mask = (const float*)d_in[1];
    const float* enc      = (const float*)d_in[2];
    const float* enc_mask = (const float*)d_in[3];
    const int*   gt       = (const int*)d_in[4];
    const float* go       = (const float*)d_in[5];
    const float* Wih      = (const float*)d_in[6];
    const float* Whh      = (const float*)d_in[7];
    const float* bih      = (const float*)d_in[8];
    const float* bhh      = (const float*)d_in[9];
    const float* Wdt      = (const float*)d_in[10];
    const float* bdt      = (const float*)d_in[11];
    const float* Wf       = (const float*)d_in[12];
    const float* bf       = (const float*)d_in[13];
    float* out = (float*)d_out;

    float* ws    = (float*)d_ws;
    float* xW    = ws;                                   // [B*T*G]
    float* dec   = xW   + (size_t)BB * TT * GG;          // [B*T*D]
    float* attn  = dec  + (size_t)BB * TT * DD;          // [B*T*D]
    float* feat  = attn + (size_t)BB * TT * DD;          // [B*T*FLD]
    float* part  = feat + (size_t)BB * TT * FLD;         // [B*8*T*D]
    float* lsum  = part + (size_t)BB * 8 * TT * DD;      // [B*8*T]
    int* firstpos = (int*)(lsum + (size_t)BB * 8 * TT);  // [B*N]
    unsigned int* hbuf32 = (unsigned int*)(firstpos + (size_t)BB * NN_); // [T*4096]
    unsigned int* hs16   = hbuf32 + (size_t)TT * 4096;   // [B*T*128]

    // prep: firstpos scan + hbuf/hs16 poison
    k_prep<<<256, 256, 0, stream>>>(gt, firstpos, hbuf32);

    // xW = x @ Wih^T + bih + bhh (gather fused) : [2048,1024]
    gemm_xw<<<dim3(GG / 64, BB * TT / 64, 1), 256, 0, stream>>>(
        emb, gt, go, Wih, xW, bih, bhh);

    // LSTM + fused dec
    k_lstm_mfma<<<LP, 256, 0, stream>>>(xW, Whh, hbuf32, hs16, Wdt, bdt, dec);

    // fused attention: partials over 8 s-chunks per batch, then merge
    k_flash<<<dim3(8, 1, BB), 256, 0, stream>>>(dec, enc, enc_mask, part, lsum);
    k_amerge<<<BB * TT, 256, 0, stream>>>(part, lsum, attn);

    // feat = [hs16|attn] @ Wf^T + bf : [2048, 257] (cat fused, ld FLD)
    gemm_feat<<<dim3(5, BB * TT / 64, 1), 256, 0, stream>>>(
        hs16, attn, Wf, bf, feat);

    // score[b] = feat[b,:, :256] @ emb[b]^T (+ picked, mask)
    gemm_bf16_nt<<<dim3(NN_ / 64, 1, BB), 256, 0, stream>>>(
        feat, emb, out, DD, FLD, DD, NN_,
        (long)TT * FLD, (long)NN_ * DD, (long)TT * NN_, NN_,
        nullptr, firstpos, emb_mask, 256);
}

// Round 17
// 249.521 us; speedup vs baseline: 7.4819x; 1.0522x over previous
//
#include <hip/hip_runtime.h>
#include <cstddef>

#define BB 32
#define TT 64
#define NN_ 2048
#define SS 2048
#define DD 256
#define GG 1024
#define LP 32   // LSTM blocks (col-slices)
#define FLD 264 // padded feat leading dim (16B-aligned rows, >=258)

typedef __attribute__((ext_vector_type(8))) short short8;
typedef __attribute__((ext_vector_type(4))) float f32x4;

static __device__ inline unsigned short f2bf(float f) {
    union { float f; unsigned int u; } v; v.f = f;
    unsigned int u = v.u;
    unsigned int r = u + 0x7FFF + ((u >> 16) & 1);   // RNE
    return (unsigned short)(r >> 16);
}

static __device__ inline short8 pack8(float4 a, float4 b) {
    short8 s;
    s[0] = (short)f2bf(a.x); s[1] = (short)f2bf(a.y);
    s[2] = (short)f2bf(a.z); s[3] = (short)f2bf(a.w);
    s[4] = (short)f2bf(b.x); s[5] = (short)f2bf(b.y);
    s[6] = (short)f2bf(b.z); s[7] = (short)f2bf(b.w);
    return s;
}

// true iff neither 16-bit half of v equals 0x7F80 (bf16 +inf sentinel)
static __device__ inline bool ok32(unsigned int v) {
    unsigned int x = v ^ 0x7F807F80u;
    return (((x - 0x00010001u) & ~x & 0x80008000u) == 0u);
}

// ---------------- prep: firstpos (scan, no atomics) + hbuf poison ----------
__global__ __launch_bounds__(256) void k_prep(const int* __restrict__ gt,
                                              int* __restrict__ firstpos,
                                              unsigned int* __restrict__ hbuf32) {
    int T = blockIdx.x * 256 + threadIdx.x;   // 0..65535 over B*N
    int b = T >> 11, n = T & 2047;
    const int* g = gt + b * TT;
    int ft = TT;
#pragma unroll
    for (int t = 0; t < TT; ++t)
        if (g[t] == n && t < ft) ft = t;
    firstpos[T] = ft;
#pragma unroll
    for (int k = 0; k < 4; ++k)
        hbuf32[T + 65536 * k] = 0x7F807F80u;   // bf16 +inf pairs
}

// ---------------- xW GEMM with fused teacher-forcing gather ----------------
__global__ __launch_bounds__(256) void gemm_xw(
        const float* __restrict__ emb, const int* __restrict__ gt,
        const float* __restrict__ go, const float* __restrict__ Wih,
        float* __restrict__ xW,
        const float* __restrict__ bih, const float* __restrict__ bhh) {
    int tm = blockIdx.y * 64, tn = blockIdx.x * 64;
    __shared__ short Ab[64][72];
    __shared__ short Bb[64][72];
    int tid = threadIdx.x, lane = tid & 63, wid = tid >> 6;
    int wm = wid & 1, wn = wid >> 1;
    f32x4 zero = {0.f, 0.f, 0.f, 0.f};
    f32x4 acc[2][2] = {{zero, zero}, {zero, zero}};
    int row = tid >> 2, kk = (tid & 3) * 16;
    int m = tm + row, b = m >> 6, t = m & 63;
    const float* arow = (t == 0) ? go
        : emb + ((size_t)b * NN_ + gt[b * TT + t - 1]) * DD;
    const float* ap = arow + kk;
    const float* bp = Wih + (size_t)(tn + row) * DD + kk;

    for (int k0 = 0; k0 < DD; k0 += 64) {
        float4 a0 = *(const float4*)(ap + k0);
        float4 a1 = *(const float4*)(ap + k0 + 4);
        float4 a2 = *(const float4*)(ap + k0 + 8);
        float4 a3 = *(const float4*)(ap + k0 + 12);
        float4 b0 = *(const float4*)(bp + k0);
        float4 b1 = *(const float4*)(bp + k0 + 4);
        float4 b2 = *(const float4*)(bp + k0 + 8);
        float4 b3 = *(const float4*)(bp + k0 + 12);
        *(short8*)&Ab[row][kk]     = pack8(a0, a1);
        *(short8*)&Ab[row][kk + 8] = pack8(a2, a3);
        *(short8*)&Bb[row][kk]     = pack8(b0, b1);
        *(short8*)&Bb[row][kk + 8] = pack8(b2, b3);
        __syncthreads();
#pragma unroll
        for (int kt = 0; kt < 2; ++kt) {
            int k8 = kt * 32 + (lane >> 4) * 8;
            short8 fa0 = *(const short8*)&Ab[wm * 32 + (lane & 15)][k8];
            short8 fa1 = *(const short8*)&Ab[wm * 32 + 16 + (lane & 15)][k8];
            short8 fb0 = *(const short8*)&Bb[wn * 32 + (lane & 15)][k8];
            short8 fb1 = *(const short8*)&Bb[wn * 32 + 16 + (lane & 15)][k8];
            acc[0][0] = __builtin_amdgcn_mfma_f32_16x16x32_bf16(fa0, fb0, acc[0][0], 0, 0, 0);
            acc[0][1] = __builtin_amdgcn_mfma_f32_16x16x32_bf16(fa0, fb1, acc[0][1], 0, 0, 0);
            acc[1][0] = __builtin_amdgcn_mfma_f32_16x16x32_bf16(fa1, fb0, acc[1][0], 0, 0, 0);
            acc[1][1] = __builtin_amdgcn_mfma_f32_16x16x32_bf16(fa1, fb1, acc[1][1], 0, 0, 0);
        }
        __syncthreads();
    }

#pragma unroll
    for (int i = 0; i < 2; ++i)
#pragma unroll
        for (int j = 0; j < 2; ++j)
#pragma unroll
            for (int r = 0; r < 4; ++r) {
                int lrow = wm * 32 + i * 16 + (lane >> 4) * 4 + r;
                int gcol = tn + wn * 32 + j * 16 + (lane & 15);
                xW[(size_t)(tm + lrow) * GG + gcol] =
                    acc[i][j][r] + bih[gcol] + bhh[gcol];
            }
}

// ---------------- generic bf16 MFMA NT GEMM (f32 A/B) ----------------------
__global__ __launch_bounds__(256) void gemm_bf16_nt(
        const float* __restrict__ A, const float* __restrict__ Bm,
        float* __restrict__ C, int K, int lda, int ldb, int ldc,
        long sA, long sB, long sC, int Nlim,
        const float* __restrict__ bias1,
        const int* __restrict__ firstpos, const float* __restrict__ emb_mask,
        int fscol) {
    int bz = blockIdx.z;
    A += (size_t)bz * sA; Bm += (size_t)bz * sB; C += (size_t)bz * sC;
    int tm = blockIdx.y * 64, tn = blockIdx.x * 64;
    __shared__ short Ab[64][72];
    __shared__ short Bb[64][72];
    __shared__ float sfs[64];
    int tid = threadIdx.x, lane = tid & 63, wid = tid >> 6;
    int wm = wid & 1, wn = wid >> 1;

    if (fscol >= 0 && tid < 64) sfs[tid] = A[(size_t)(tm + tid) * lda + fscol];

    f32x4 zero = {0.f, 0.f, 0.f, 0.f};
    f32x4 acc[2][2] = {{zero, zero}, {zero, zero}};

    int row = tid >> 2, kk = (tid & 3) * 16;
    int brow = tn + row; if (brow >= Nlim) brow = Nlim - 1;
    const float* ap = &A[(size_t)(tm + row) * lda + kk];
    const float* bp = &Bm[(size_t)brow * ldb + kk];

    for (int k0 = 0; k0 < K; k0 += 64) {
        float4 a0 = *(const float4*)(ap + k0);
        float4 a1 = *(const float4*)(ap + k0 + 4);
        float4 a2 = *(const float4*)(ap + k0 + 8);
        float4 a3 = *(const float4*)(ap + k0 + 12);
        float4 b0 = *(const float4*)(bp + k0);
        float4 b1 = *(const float4*)(bp + k0 + 4);
        float4 b2 = *(const float4*)(bp + k0 + 8);
        float4 b3 = *(const float4*)(bp + k0 + 12);
        *(short8*)&Ab[row][kk]     = pack8(a0, a1);
        *(short8*)&Ab[row][kk + 8] = pack8(a2, a3);
        *(short8*)&Bb[row][kk]     = pack8(b0, b1);
        *(short8*)&Bb[row][kk + 8] = pack8(b2, b3);
        __syncthreads();
#pragma unroll
        for (int kt = 0; kt < 2; ++kt) {
            int k8 = kt * 32 + (lane >> 4) * 8;
            short8 fa0 = *(const short8*)&Ab[wm * 32 + (lane & 15)][k8];
            short8 fa1 = *(const short8*)&Ab[wm * 32 + 16 + (lane & 15)][k8];
            short8 fb0 = *(const short8*)&Bb[wn * 32 + (lane & 15)][k8];
            short8 fb1 = *(const short8*)&Bb[wn * 32 + 16 + (lane & 15)][k8];
            acc[0][0] = __builtin_amdgcn_mfma_f32_16x16x32_bf16(fa0, fb0, acc[0][0], 0, 0, 0);
            acc[0][1] = __builtin_amdgcn_mfma_f32_16x16x32_bf16(fa0, fb1, acc[0][1], 0, 0, 0);
            acc[1][0] = __builtin_amdgcn_mfma_f32_16x16x32_bf16(fa1, fb0, acc[1][0], 0, 0, 0);
            acc[1][1] = __builtin_amdgcn_mfma_f32_16x16x32_bf16(fa1, fb1, acc[1][1], 0, 0, 0);
        }
        __syncthreads();
    }

#pragma unroll
    for (int i = 0; i < 2; ++i) {
#pragma unroll
        for (int j = 0; j < 2; ++j) {
#pragma unroll
            for (int r = 0; r < 4; ++r) {
                int lrow = wm * 32 + i * 16 + (lane >> 4) * 4 + r;
                int gcol = tn + wn * 32 + j * 16 + (lane & 15);
                if (gcol < Nlim) {
                    float v = acc[i][j][r];
                    if (bias1) v += bias1[gcol];
                    if (firstpos) {
                        int grow = tm + lrow;
                        if (firstpos[(size_t)bz * NN_ + gcol] < grow) v += sfs[lrow];
                        v -= (1.0f - emb_mask[(size_t)bz * NN_ + gcol]) * 1e20f;
                    }
                    C[(size_t)(tm + lrow) * ldc + gcol] = v;
                }
            }
        }
    }
}

// ---------------- dec = hs16(bf16) @ Wdt^T + bdt ---------------------------
__global__ __launch_bounds__(256) void gemm_dec(
        const unsigned int* __restrict__ hs16, const float* __restrict__ Wdt,
        float* __restrict__ dec, const float* __restrict__ bdt) {
    int tm = blockIdx.y * 64, tn = blockIdx.x * 64;
    __shared__ short Ab[64][72];
    __shared__ short Bb[64][72];
    int tid = threadIdx.x, lane = tid & 63, wid = tid >> 6;
    int wm = wid & 1, wn = wid >> 1;
    f32x4 zero = {0.f, 0.f, 0.f, 0.f};
    f32x4 acc[2][2] = {{zero, zero}, {zero, zero}};
    int row = tid >> 2, kk = (tid & 3) * 16;
    const short* ap16 = (const short*)hs16 + (size_t)(tm + row) * DD + kk;
    const float* bp = Wdt + (size_t)(tn + row) * DD + kk;

    for (int k0 = 0; k0 < DD; k0 += 64) {
        *(short8*)&Ab[row][kk]     = *(const short8*)(ap16 + k0);
        *(short8*)&Ab[row][kk + 8] = *(const short8*)(ap16 + k0 + 8);
        float4 b0 = *(const float4*)(bp + k0);
        float4 b1 = *(const float4*)(bp + k0 + 4);
        float4 b2 = *(const float4*)(bp + k0 + 8);
        float4 b3 = *(const float4*)(bp + k0 + 12);
        *(short8*)&Bb[row][kk]     = pack8(b0, b1);
        *(short8*)&Bb[row][kk + 8] = pack8(b2, b3);
        __syncthreads();
#pragma unroll
        for (int kt = 0; kt < 2; ++kt) {
            int k8 = kt * 32 + (lane >> 4) * 8;
            short8 fa0 = *(const short8*)&Ab[wm * 32 + (lane & 15)][k8];
            short8 fa1 = *(const short8*)&Ab[wm * 32 + 16 + (lane & 15)][k8];
            short8 fb0 = *(const short8*)&Bb[wn * 32 + (lane & 15)][k8];
            short8 fb1 = *(const short8*)&Bb[wn * 32 + 16 + (lane & 15)][k8];
            acc[0][0] = __builtin_amdgcn_mfma_f32_16x16x32_bf16(fa0, fb0, acc[0][0], 0, 0, 0);
            acc[0][1] = __builtin_amdgcn_mfma_f32_16x16x32_bf16(fa0, fb1, acc[0][1], 0, 0, 0);
            acc[1][0] = __builtin_amdgcn_mfma_f32_16x16x32_bf16(fa1, fb0, acc[1][0], 0, 0, 0);
            acc[1][1] = __builtin_amdgcn_mfma_f32_16x16x32_bf16(fa1, fb1, acc[1][1], 0, 0, 0);
        }
        __syncthreads();
    }

#pragma unroll
    for (int i = 0; i < 2; ++i)
#pragma unroll
        for (int j = 0; j < 2; ++j)
#pragma unroll
            for (int r = 0; r < 4; ++r) {
                int lrow = wm * 32 + i * 16 + (lane >> 4) * 4 + r;
                int gcol = tn + wn * 32 + j * 16 + (lane & 15);
                dec[(size_t)(tm + lrow) * DD + gcol] = acc[i][j][r] + bdt[gcol];
            }
}

// ---------------- feat = [hs16 | attn] @ Wf^T + bf (fused cat) -------------
__global__ __launch_bounds__(256) void gemm_feat(
        const unsigned int* __restrict__ hs16, const float* __restrict__ attn,
        const float* __restrict__ Wf, const float* __restrict__ bf,
        float* __restrict__ feat) {
    int tm = blockIdx.y * 64, tn = blockIdx.x * 64;
    __shared__ short Ab[64][72];
    __shared__ short Bb[64][72];
    int tid = threadIdx.x, lane = tid & 63, wid = tid >> 6;
    int wm = wid & 1, wn = wid >> 1;
    f32x4 zero = {0.f, 0.f, 0.f, 0.f};
    f32x4 acc[2][2] = {{zero, zero}, {zero, zero}};
    int row = tid >> 2, kk = (tid & 3) * 16;
    int brow = tn + row; if (brow > 256) brow = 256;
    const short* a16 = (const short*)hs16 + (size_t)(tm + row) * DD + kk;
    const float* af  = attn + (size_t)(tm + row) * DD + kk;
    const float* bp  = Wf + (size_t)brow * (2 * DD) + kk;

    for (int k0 = 0; k0 < 2 * DD; k0 += 64) {
        if (k0 < DD) {
            *(short8*)&Ab[row][kk]     = *(const short8*)(a16 + k0);
            *(short8*)&Ab[row][kk + 8] = *(const short8*)(a16 + k0 + 8);
        } else {
            float4 a0 = *(const float4*)(af + k0 - DD);
            float4 a1 = *(const float4*)(af + k0 - DD + 4);
            float4 a2 = *(const float4*)(af + k0 - DD + 8);
            float4 a3 = *(const float4*)(af + k0 - DD + 12);
            *(short8*)&Ab[row][kk]     = pack8(a0, a1);
            *(short8*)&Ab[row][kk + 8] = pack8(a2, a3);
        }
        float4 b0 = *(const float4*)(bp + k0);
        float4 b1 = *(const float4*)(bp + k0 + 4);
        float4 b2 = *(const float4*)(bp + k0 + 8);
        float4 b3 = *(const float4*)(bp + k0 + 12);
        *(short8*)&Bb[row][kk]     = pack8(b0, b1);
        *(short8*)&Bb[row][kk + 8] = pack8(b2, b3);
        __syncthreads();
#pragma unroll
        for (int kt = 0; kt < 2; ++kt) {
            int k8 = kt * 32 + (lane >> 4) * 8;
            short8 fa0 = *(const short8*)&Ab[wm * 32 + (lane & 15)][k8];
            short8 fa1 = *(const short8*)&Ab[wm * 32 + 16 + (lane & 15)][k8];
            short8 fb0 = *(const short8*)&Bb[wn * 32 + (lane & 15)][k8];
            short8 fb1 = *(const short8*)&Bb[wn * 32 + 16 + (lane & 15)][k8];
            acc[0][0] = __builtin_amdgcn_mfma_f32_16x16x32_bf16(fa0, fb0, acc[0][0], 0, 0, 0);
            acc[0][1] = __builtin_amdgcn_mfma_f32_16x16x32_bf16(fa0, fb1, acc[0][1], 0, 0, 0);
            acc[1][0] = __builtin_amdgcn_mfma_f32_16x16x32_bf16(fa1, fb0, acc[1][0], 0, 0, 0);
            acc[1][1] = __builtin_amdgcn_mfma_f32_16x16x32_bf16(fa1, fb1, acc[1][1], 0, 0, 0);
        }
        __syncthreads();
    }

#pragma unroll
    for (int i = 0; i < 2; ++i)
#pragma unroll
        for (int j = 0; j < 2; ++j)
#pragma unroll
            for (int r = 0; r < 4; ++r) {
                int lrow = wm * 32 + i * 16 + (lane >> 4) * 4 + r;
                int gcol = tn + wn * 32 + j * 16 + (lane & 15);
                if (gcol < DD + 1)
                    feat[(size_t)(tm + lrow) * FLD + gcol] = acc[i][j][r] + bf[gcol];
            }
}

// ---------------- flash attention: raw+softmax+attn fused ------------------
// Block (c, b): s-chunk c (256 s-positions) of batch b. No max-subtraction
// (softmax is shift-invariant; |raw| small so exp stays in f32 range).
__global__ __launch_bounds__(256) void k_flash(const float* __restrict__ dec,
                                               const float* __restrict__ enc,
                                               const float* __restrict__ enc_mask,
                                               float* __restrict__ part,
                                               float* __restrict__ lsum) {
    int c = blockIdx.x;            // s-chunk 0..7
    int b = blockIdx.z;
    const float* Qf = dec + (size_t)b * TT * DD;
    const float* Eb = enc + (size_t)b * SS * DD;

    __shared__ short Vt[64][264];  // enc tile bf16 [s][d]
    __shared__ short Pt[64][72];   // P bf16 [t][s]
    __shared__ float l_run[64][2];
    __shared__ float smsk[64];

    int tid = threadIdx.x, lane = tid & 63, wid = tid >> 6;
    int wm = wid & 1, wn = wid >> 1;
    int row = tid >> 2, kk = (tid & 3) * 16;

    short8 qf[8][2];
#pragma unroll
    for (int kt = 0; kt < 8; ++kt) {
        int kb = kt * 32 + (lane >> 4) * 8;
        const float* q0 = Qf + (size_t)(wm * 32 + (lane & 15)) * DD + kb;
        const float* q1 = Qf + (size_t)(wm * 32 + 16 + (lane & 15)) * DD + kb;
        qf[kt][0] = pack8(*(const float4*)q0, *(const float4*)(q0 + 4));
        qf[kt][1] = pack8(*(const float4*)q1, *(const float4*)(q1 + 4));
    }

    if (tid < 128) ((float*)l_run)[tid] = 0.0f;

    f32x4 zero = {0.f, 0.f, 0.f, 0.f};
    f32x4 aO[4][2][2];
#pragma unroll
    for (int dp = 0; dp < 4; ++dp)
#pragma unroll
        for (int i = 0; i < 2; ++i)
#pragma unroll
            for (int j = 0; j < 2; ++j) aO[dp][i][j] = zero;

    for (int kt64 = 0; kt64 < 4; ++kt64) {
        int s0 = c * 256 + kt64 * 64;
        __syncthreads();
#pragma unroll
        for (int kq = 0; kq < 4; ++kq) {
            const float* e = Eb + (size_t)(s0 + row) * DD + kq * 64 + kk;
            float4 e0 = *(const float4*)e;
            float4 e1 = *(const float4*)(e + 4);
            float4 e2 = *(const float4*)(e + 8);
            float4 e3 = *(const float4*)(e + 12);
            *(short8*)&Vt[row][kq * 64 + kk]     = pack8(e0, e1);
            *(short8*)&Vt[row][kq * 64 + kk + 8] = pack8(e2, e3);
        }
        if (tid < 64) smsk[tid] = enc_mask[(size_t)b * SS + s0 + tid];
        __syncthreads();

        f32x4 aS[2][2] = {{zero, zero}, {zero, zero}};
#pragma unroll
        for (int kt = 0; kt < 8; ++kt) {
            int k8 = kt * 32 + (lane >> 4) * 8;
            short8 fb0 = *(const short8*)&Vt[wn * 32 + (lane & 15)][k8];
            short8 fb1 = *(const short8*)&Vt[wn * 32 + 16 + (lane & 15)][k8];
            aS[0][0] = __builtin_amdgcn_mfma_f32_16x16x32_bf16(qf[kt][0], fb0, aS[0][0], 0, 0, 0);
            aS[0][1] = __builtin_amdgcn_mfma_f32_16x16x32_bf16(qf[kt][0], fb1, aS[0][1], 0, 0, 0);
            aS[1][0] = __builtin_amdgcn_mfma_f32_16x16x32_bf16(qf[kt][1], fb0, aS[1][0], 0, 0, 0);
            aS[1][1] = __builtin_amdgcn_mfma_f32_16x16x32_bf16(qf[kt][1], fb1, aS[1][1], 0, 0, 0);
        }

        int scol0 = wn * 32 + (lane & 15);
        float pen0 = (1.0f - smsk[scol0]) * 1e20f;
        float pen1 = (1.0f - smsk[scol0 + 16]) * 1e20f;
#pragma unroll
        for (int i = 0; i < 2; ++i)
#pragma unroll
            for (int r = 0; r < 4; ++r) {
                float p0 = __expf(aS[i][0][r] - pen0);
                float p1 = __expf(aS[i][1][r] - pen1);
                int trow = wm * 32 + i * 16 + (lane >> 4) * 4 + r;
                Pt[trow][scol0] = (short)f2bf(p0);
                Pt[trow][scol0 + 16] = (short)f2bf(p1);
                float rs = p0 + p1;
                rs += __shfl_xor(rs, 1);
                rs += __shfl_xor(rs, 2);
                rs += __shfl_xor(rs, 4);
                rs += __shfl_xor(rs, 8);
                if ((lane & 15) == 0) l_run[trow][wn] += rs;
            }
        __syncthreads();

#pragma unroll
        for (int kt = 0; kt < 2; ++kt) {
            int k8 = kt * 32 + (lane >> 4) * 8;
            short8 fa0 = *(const short8*)&Pt[wm * 32 + (lane & 15)][k8];
            short8 fa1 = *(const short8*)&Pt[wm * 32 + 16 + (lane & 15)][k8];
#pragma unroll
            for (int dp = 0; dp < 4; ++dp) {
                int dc = dp * 64 + wn * 32 + (lane & 15);
                short8 fb0, fb1;
#pragma unroll
                for (int e = 0; e < 8; ++e) {
                    fb0[e] = Vt[k8 + e][dc];
                    fb1[e] = Vt[k8 + e][dc + 16];
                }
                aO[dp][0][0] = __builtin_amdgcn_mfma_f32_16x16x32_bf16(fa0, fb0, aO[dp][0][0], 0, 0, 0);
                aO[dp][0][1] = __builtin_amdgcn_mfma_f32_16x16x32_bf16(fa0, fb1, aO[dp][0][1], 0, 0, 0);
                aO[dp][1][0] = __builtin_amdgcn_mfma_f32_16x16x32_bf16(fa1, fb0, aO[dp][1][0], 0, 0, 0);
                aO[dp][1][1] = __builtin_amdgcn_mfma_f32_16x16x32_bf16(fa1, fb1, aO[dp][1][1], 0, 0, 0);
            }
        }
    }
    __syncthreads();

    float* pp = part + ((size_t)(b * 8 + c) * 64) * 256;
#pragma unroll
    for (int dp = 0; dp < 4; ++dp)
#pragma unroll
        for (int i = 0; i < 2; ++i)
#pragma unroll
            for (int j = 0; j < 2; ++j)
#pragma unroll
                for (int r = 0; r < 4; ++r) {
                    int trow = wm * 32 + i * 16 + (lane >> 4) * 4 + r;
                    int dcol = dp * 64 + wn * 32 + j * 16 + (lane & 15);
                    pp[(size_t)trow * 256 + dcol] = aO[dp][i][j][r];
                }
    if (tid < 64)
        lsum[(size_t)(b * 8 + c) * 64 + tid] = l_run[tid][0] + l_run[tid][1];
}

// ---------------- merge flash partials: attn = sum acc_c / sum l_c ---------
__global__ __launch_bounds__(256) void k_amerge(const float* __restrict__ part,
                                                const float* __restrict__ lsum,
                                                float* __restrict__ attn) {
    int bt = blockIdx.x;           // 0..2047
    int b = bt >> 6, t = bt & 63, d = threadIdx.x;
    float a = 0.0f, L = 0.0f;
#pragma unroll
    for (int c = 0; c < 8; ++c) {
        a += part[((size_t)(b * 8 + c) * 64 + t) * 256 + d];
        L += lsum[(size_t)(b * 8 + c) * 64 + t];
    }
    attn[(size_t)bt * 256 + d] = a / L;
}

// ---------------- LSTM (proven round-6/11): transposed MFMA, in-lane act ---
__global__ __launch_bounds__(256) void k_lstm_mfma(const float* __restrict__ xW,
                                                   const float* __restrict__ Whh,
                                                   unsigned int* __restrict__ hbuf32,
                                                   unsigned int* __restrict__ hs16) {
    int p = blockIdx.x;            // 0..31 col-slice
    int tid = threadIdx.x;
    int lane = tid & 63;
    int wid = tid >> 6;            // 4 waves
    int mi = wid & 1;              // unit-halves (4 units each)
    int ni = wid >> 1;             // batch-halves (16 batches each)
    int jj = lane >> 4;            // 0..3 unit within mi-group
    int bl = lane & 15;            // batch within ni-group
    int j = p * 8 + mi * 4 + jj;   // hidden unit this lane activates
    int b = ni * 16 + bl;          // batch this lane activates

    short8 afrag[8];
    {
        int rr = lane & 15;
        const float* wrow = Whh + (size_t)((rr & 3) * 256 + p * 8 + mi * 4 + (rr >> 2)) * DD;
#pragma unroll
        for (int kt = 0; kt < 8; ++kt) {
            short8 f;
#pragma unroll
            for (int e = 0; e < 8; ++e)
                f[e] = (short)f2bf(wrow[kt * 32 + (lane >> 4) * 8 + e]);
            afrag[kt] = f;
        }
    }

    float cstate = 0.0f;
    const int wb = jj * 128 + b;   // word base: (jj*4 + w4)*32 + b

    for (int t = 0; t < TT; ++t) {
        const float* g0 = xW + ((size_t)b * TT + t) * GG + j;
        float xb0 = g0[0], xb1 = g0[256], xb2 = g0[512], xb3 = g0[768];

        f32x4 acc = {0.f, 0.f, 0.f, 0.f};
        if (t > 0) {
            const unsigned int* hb = hbuf32 + (size_t)(t - 1) * 4096;
            unsigned int q[32];
            bool ready = false;
            while (!ready) {
                ready = true;
#pragma unroll
                for (int kt = 0; kt < 8; ++kt)
#pragma unroll
                    for (int w4 = 0; w4 < 4; ++w4)
                        q[kt * 4 + w4] = __hip_atomic_load(&hb[kt * 512 + wb + w4 * 32],
                            __ATOMIC_RELAXED, __HIP_MEMORY_SCOPE_AGENT);
#pragma unroll
                for (int i = 0; i < 32; ++i) ready = ready && ok32(q[i]);
            }
#pragma unroll
            for (int kt = 0; kt < 8; ++kt) {
                union { unsigned int w[4]; short8 s; } u;
                u.w[0] = q[kt * 4 + 0]; u.w[1] = q[kt * 4 + 1];
                u.w[2] = q[kt * 4 + 2]; u.w[3] = q[kt * 4 + 3];
                acc = __builtin_amdgcn_mfma_f32_16x16x32_bf16(afrag[kt], u.s, acc, 0, 0, 0);
            }
        }

        float pi = xb0 + acc[0];
        float pf = xb1 + acc[1];
        float pg = xb2 + acc[2];
        float po = xb3 + acc[3];
        float ig = 1.0f / (1.0f + __expf(-pi));
        float fg = 1.0f / (1.0f + __expf(-pf));
        float gg = tanhf(pg);
        float og = 1.0f / (1.0f + __expf(-po));
        cstate = fg * cstate + ig * gg;
        float hn = og * tanhf(cstate);

        float hnb = __shfl_down(hn, 16);
        if ((jj & 1) == 0) {
            unsigned int wv = (unsigned int)f2bf(hn) |
                              ((unsigned int)f2bf(hnb) << 16);
            int jp = p * 4 + mi * 2 + (jj >> 1);
            __hip_atomic_store(&hbuf32[(size_t)t * 4096 + jp * 32 + b],
                               wv, __ATOMIC_RELAXED, __HIP_MEMORY_SCOPE_AGENT);
            hs16[((size_t)b * TT + t) * 128 + jp] = wv;   // row-major bf16 hs
        }
        asm volatile("s_waitcnt vmcnt(0)" ::: "memory");
    }
}

// ---------------- launch ----------------
extern "C" void kernel_launch(void* const* d_in, const int* in_sizes, int n_in,
                              void* d_out, int out_size, void* d_ws, size_t ws_size,
                              hipStream_t stream) {
    const float* emb      = (const float*)d_in[0];
    const float* emb_mask = (const float*)d_in[1];
    const float* enc      = (const float*)d_in[2];
    const float* enc_mask = (const float*)d_in[3];
    const int*   gt       = (const int*)d_in[4];
    const float* go       = (const float*)d_in[5];
    const float* Wih      = (const float*)d_in[6];
    const float* Whh      = (const float*)d_in[7];
    const float* bih      = (const float*)d_in[8];
    const float* bhh      = (const float*)d_in[9];
    const float* Wdt      = (const float*)d_in[10];
    const float* bdt      = (const float*)d_in[11];
    const float* Wf       = (const float*)d_in[12];
    const float* bf       = (const float*)d_in[13];
    float* out = (float*)d_out;

    float* ws    = (float*)d_ws;
    float* xW    = ws;                                   // [B*T*G]
    float* dec   = xW   + (size_t)BB * TT * GG;          // [B*T*D]
    float* attn  = dec  + (size_t)BB * TT * DD;          // [B*T*D]
    float* feat  = attn + (size_t)BB * TT * DD;          // [B*T*FLD]
    float* part  = feat + (size_t)BB * TT * FLD;         // [B*8*T*D]
    float* lsum  = part + (size_t)BB * 8 * TT * DD;      // [B*8*T]
    int* firstpos = (int*)(lsum + (size_t)BB * 8 * TT);  // [B*N]
    unsigned int* hbuf32 = (unsigned int*)(firstpos + (size_t)BB * NN_); // [T*4096]
    unsigned int* hs16   = hbuf32 + (size_t)TT * 4096;   // [B*T*128]

    // prep: firstpos scan + hbuf poison
    k_prep<<<256, 256, 0, stream>>>(gt, firstpos, hbuf32);

    // xW = x @ Wih^T + bih + bhh (gather fused) : [2048,1024]
    gemm_xw<<<dim3(GG / 64, BB * TT / 64, 1), 256, 0, stream>>>(
        emb, gt, go, Wih, xW, bih, bhh);

    k_lstm_mfma<<<LP, 256, 0, stream>>>(xW, Whh, hbuf32, hs16);

    // dec = hs16 @ Wdt^T + bdt : [2048,256]
    gemm_dec<<<dim3(DD / 64, BB * TT / 64, 1), 256, 0, stream>>>(
        hs16, Wdt, dec, bdt);

    // fused attention: partials over 8 s-chunks per batch, then merge
    k_flash<<<dim3(8, 1, BB), 256, 0, stream>>>(dec, enc, enc_mask, part, lsum);
    k_amerge<<<BB * TT, 256, 0, stream>>>(part, lsum, attn);

    // feat = [hs16|attn] @ Wf^T + bf : [2048, 257] (cat fused, ld FLD)
    gemm_feat<<<dim3(5, BB * TT / 64, 1), 256, 0, stream>>>(
        hs16, attn, Wf, bf, feat);

    // score[b] = feat[b,:, :256] @ emb[b]^T (+ picked, mask)
    gemm_bf16_nt<<<dim3(NN_ / 64, 1, BB), 256, 0, stream>>>(
        feat, emb, out, DD, FLD, DD, NN_,
        (long)TT * FLD, (long)NN_ * DD, (long)TT * NN_, NN_,
        nullptr, firstpos, emb_mask, 256);
}